// Round 1
// baseline (511.768 us; speedup 1.0000x reference)
//
#include <hip/hip_runtime.h>

#define BB 32
#define IDF 64
#define CDF 256
#define SSZ 1024
#define NH 8
#define LL 256

// ---------------------------------------------------------------------------
// K1: M[bh][i][c] = sum_o wc[b][i][o] * W[h][o][c]     (64x256, K=1024)
// ---------------------------------------------------------------------------
__global__ __launch_bounds__(256) void k_gemm_M(const float* __restrict__ wc,
                                                const float* __restrict__ Wt,
                                                float* __restrict__ Mout) {
  __shared__ float As[IDF][32];   // [i][k]  k-contiguous
  __shared__ float Bs[32][CDF];   // [k][c]  c-contiguous
  int bh = blockIdx.x; int b = bh >> 3, h = bh & 7;
  const float* A  = wc + (size_t)b * IDF * SSZ;
  const float* Bm = Wt + (size_t)h * SSZ * CDF;
  int tid = threadIdx.x;
  int tc = tid & 31, ti = tid >> 5;
  int c0 = tc * 8, i0 = ti * 8;
  float acc[8][8];
#pragma unroll
  for (int r = 0; r < 8; ++r)
#pragma unroll
    for (int s = 0; s < 8; ++s) acc[r][s] = 0.f;

  for (int k0 = 0; k0 < SSZ; k0 += 32) {
#pragma unroll
    for (int p = 0; p < 2; ++p) {            // A tile: 64 rows x 8 f4
      int f = tid + p * 256;
      int row = f >> 3, seg = f & 7;
      *reinterpret_cast<float4*>(&As[row][seg * 4]) =
          *reinterpret_cast<const float4*>(&A[row * SSZ + k0 + seg * 4]);
    }
#pragma unroll
    for (int p = 0; p < 8; ++p) {            // B tile: 32 rows x 64 f4
      int f = tid + p * 256;
      int kk = f >> 6, cs = f & 63;
      *reinterpret_cast<float4*>(&Bs[kk][cs * 4]) =
          *reinterpret_cast<const float4*>(&Bm[(size_t)(k0 + kk) * CDF + cs * 4]);
    }
    __syncthreads();
#pragma unroll
    for (int kq = 0; kq < 8; ++kq) {
      float4 av[8];
#pragma unroll
      for (int r = 0; r < 8; ++r)
        av[r] = *reinterpret_cast<const float4*>(&As[i0 + r][kq * 4]);
#pragma unroll
      for (int kk = 0; kk < 4; ++kk) {
        float4 b0 = *reinterpret_cast<const float4*>(&Bs[kq * 4 + kk][c0]);
        float4 b1 = *reinterpret_cast<const float4*>(&Bs[kq * 4 + kk][c0 + 4]);
        float bv[8] = {b0.x, b0.y, b0.z, b0.w, b1.x, b1.y, b1.z, b1.w};
#pragma unroll
        for (int r = 0; r < 8; ++r) {
          float a = (kk == 0) ? av[r].x : (kk == 1) ? av[r].y : (kk == 2) ? av[r].z : av[r].w;
#pragma unroll
          for (int s = 0; s < 8; ++s) acc[r][s] += a * bv[s];
        }
      }
    }
    __syncthreads();
  }
  float* out = Mout + (size_t)bh * IDF * CDF;
#pragma unroll
  for (int r = 0; r < 8; ++r) {
    float4 v0 = {acc[r][0], acc[r][1], acc[r][2], acc[r][3]};
    float4 v1 = {acc[r][4], acc[r][5], acc[r][6], acc[r][7]};
    *reinterpret_cast<float4*>(&out[(i0 + r) * CDF + c0]) = v0;
    *reinterpret_cast<float4*>(&out[(i0 + r) * CDF + c0 + 4]) = v1;
  }
}

// ---------------------------------------------------------------------------
// K2: logits[bh][i][l] = sum_c M[bh][i][c] * ctx[b][c][l]; softmax over l;
//     write attn probs.                                    (64x256, K=256)
// ---------------------------------------------------------------------------
__global__ __launch_bounds__(256) void k_attn(const float* __restrict__ Mm,
                                              const float* __restrict__ ctx,
                                              float* __restrict__ attn) {
  __shared__ float As[IDF][32];
  __shared__ float Bs[32][LL];
  int bh = blockIdx.x; int b = bh >> 3;
  const float* A  = Mm + (size_t)bh * IDF * CDF;
  const float* Bm = ctx + (size_t)b * CDF * LL;
  int tid = threadIdx.x;
  int tc = tid & 31, ti = tid >> 5;
  int c0 = tc * 8, i0 = ti * 8;   // c0 is the l-offset here
  float acc[8][8];
#pragma unroll
  for (int r = 0; r < 8; ++r)
#pragma unroll
    for (int s = 0; s < 8; ++s) acc[r][s] = 0.f;

  for (int k0 = 0; k0 < CDF; k0 += 32) {
#pragma unroll
    for (int p = 0; p < 2; ++p) {
      int f = tid + p * 256;
      int row = f >> 3, seg = f & 7;
      *reinterpret_cast<float4*>(&As[row][seg * 4]) =
          *reinterpret_cast<const float4*>(&A[row * CDF + k0 + seg * 4]);
    }
#pragma unroll
    for (int p = 0; p < 8; ++p) {
      int f = tid + p * 256;
      int kk = f >> 6, cs = f & 63;
      *reinterpret_cast<float4*>(&Bs[kk][cs * 4]) =
          *reinterpret_cast<const float4*>(&Bm[(size_t)(k0 + kk) * LL + cs * 4]);
    }
    __syncthreads();
#pragma unroll
    for (int kq = 0; kq < 8; ++kq) {
      float4 av[8];
#pragma unroll
      for (int r = 0; r < 8; ++r)
        av[r] = *reinterpret_cast<const float4*>(&As[i0 + r][kq * 4]);
#pragma unroll
      for (int kk = 0; kk < 4; ++kk) {
        float4 b0 = *reinterpret_cast<const float4*>(&Bs[kq * 4 + kk][c0]);
        float4 b1 = *reinterpret_cast<const float4*>(&Bs[kq * 4 + kk][c0 + 4]);
        float bv[8] = {b0.x, b0.y, b0.z, b0.w, b1.x, b1.y, b1.z, b1.w};
#pragma unroll
        for (int r = 0; r < 8; ++r) {
          float a = (kk == 0) ? av[r].x : (kk == 1) ? av[r].y : (kk == 2) ? av[r].z : av[r].w;
#pragma unroll
          for (int s = 0; s < 8; ++s) acc[r][s] += a * bv[s];
        }
      }
    }
    __syncthreads();
  }
  // softmax over l: each row i lives in 32 lanes (same half-wave) x 8 regs
  float* out = attn + (size_t)bh * IDF * LL;
#pragma unroll
  for (int r = 0; r < 8; ++r) {
    float mx = acc[r][0];
#pragma unroll
    for (int s = 1; s < 8; ++s) mx = fmaxf(mx, acc[r][s]);
#pragma unroll
    for (int m = 16; m >= 1; m >>= 1) mx = fmaxf(mx, __shfl_xor(mx, m, 64));
    float ex[8]; float sum = 0.f;
#pragma unroll
    for (int s = 0; s < 8; ++s) { ex[s] = __expf(acc[r][s] - mx); sum += ex[s]; }
#pragma unroll
    for (int m = 16; m >= 1; m >>= 1) sum += __shfl_xor(sum, m, 64);
    float inv = 1.f / sum;
    float4 v0 = {ex[0] * inv, ex[1] * inv, ex[2] * inv, ex[3] * inv};
    float4 v1 = {ex[4] * inv, ex[5] * inv, ex[6] * inv, ex[7] * inv};
    *reinterpret_cast<float4*>(&out[(i0 + r) * LL + c0]) = v0;
    *reinterpret_cast<float4*>(&out[(i0 + r) * LL + c0 + 4]) = v1;
  }
}

// ---------------------------------------------------------------------------
// K3: N[bh][c][i] = sum_l ctx[b][c][l] * attn[bh][i][l]   (256x64, K=256, NT)
// ---------------------------------------------------------------------------
__global__ __launch_bounds__(256) void k_N(const float* __restrict__ ctx,
                                           const float* __restrict__ attn,
                                           float* __restrict__ Nout) {
  __shared__ float As[CDF][32];   // [c][l-chunk], chunk XOR-swizzled by (c>>3)&7
  __shared__ float Bs[IDF][32];   // [i][l]
  int bh = blockIdx.x; int b = bh >> 3;
  const float* A  = ctx + (size_t)b * CDF * LL;
  const float* Bm = attn + (size_t)bh * IDF * LL;
  int tid = threadIdx.x;
  int tc = tid & 31, ti = tid >> 5;
  int c0 = tc * 8, i0 = ti * 8;
  float acc[8][8];
#pragma unroll
  for (int r = 0; r < 8; ++r)
#pragma unroll
    for (int s = 0; s < 8; ++s) acc[r][s] = 0.f;

  for (int l0 = 0; l0 < LL; l0 += 32) {
#pragma unroll
    for (int p = 0; p < 8; ++p) {            // ctx tile: 256 rows x 8 f4, swizzled
      int f = tid + p * 256;
      int row = f >> 3, seg = f & 7;
      int ch = seg ^ ((row >> 3) & 7);
      *reinterpret_cast<float4*>(&As[row][ch * 4]) =
          *reinterpret_cast<const float4*>(&A[row * LL + l0 + seg * 4]);
    }
#pragma unroll
    for (int p = 0; p < 2; ++p) {            // attn tile: 64 rows x 8 f4
      int f = tid + p * 256;
      int row = f >> 3, seg = f & 7;
      *reinterpret_cast<float4*>(&Bs[row][seg * 4]) =
          *reinterpret_cast<const float4*>(&Bm[row * LL + l0 + seg * 4]);
    }
    __syncthreads();
#pragma unroll
    for (int kq = 0; kq < 8; ++kq) {
      float4 bv4[8];
#pragma unroll
      for (int s = 0; s < 8; ++s)
        bv4[s] = *reinterpret_cast<const float4*>(&Bs[i0 + s][kq * 4]);
      int ach = (kq ^ (tc & 7)) * 4;
#pragma unroll
      for (int r = 0; r < 8; ++r) {
        float4 a4 = *reinterpret_cast<const float4*>(&As[c0 + r][ach]);
#pragma unroll
        for (int s = 0; s < 8; ++s) {
          acc[r][s] += a4.x * bv4[s].x + a4.y * bv4[s].y +
                       a4.z * bv4[s].z + a4.w * bv4[s].w;
        }
      }
    }
    __syncthreads();
  }
  float* out = Nout + (size_t)bh * CDF * IDF;
#pragma unroll
  for (int r = 0; r < 8; ++r) {
    float4 v0 = {acc[r][0], acc[r][1], acc[r][2], acc[r][3]};
    float4 v1 = {acc[r][4], acc[r][5], acc[r][6], acc[r][7]};
    *reinterpret_cast<float4*>(&out[(c0 + r) * IDF + i0]) = v0;
    *reinterpret_cast<float4*>(&out[(c0 + r) * IDF + i0 + 4]) = v1;
  }
}

// ---------------------------------------------------------------------------
// K4: ctx_out[b][i][o] = sum_{h,c} N[b][h][c][i] * W[h][o][c]
//     per block: one b, 128-wide o tile, K = 2048                    (64x128)
// ---------------------------------------------------------------------------
__global__ __launch_bounds__(256) void k_ctxout(const float* __restrict__ Nn,
                                                const float* __restrict__ Wt,
                                                float* __restrict__ outc) {
  __shared__ float As[32][IDF];    // [k][i]
  __shared__ float Ws[32][132];    // [k(c)][o] transposed, padded
  int blk = blockIdx.x; int b = blk >> 3, ot = blk & 7;
  int o_base = ot * 128;
  const float* A = Nn + (size_t)b * NH * CDF * IDF;   // [2048][64]
  int tid = threadIdx.x;
  int to = tid & 31, ti = tid >> 5;
  int o0 = to * 4, i0 = ti * 8;
  float acc[8][4];
#pragma unroll
  for (int r = 0; r < 8; ++r)
#pragma unroll
    for (int q = 0; q < 4; ++q) acc[r][q] = 0.f;

  for (int k0 = 0; k0 < NH * CDF; k0 += 32) {
    int h = k0 >> 8;
    int c0k = k0 & 255;
#pragma unroll
    for (int p = 0; p < 2; ++p) {            // N tile: 32 rows x 16 f4
      int f = tid + p * 256;
      int kk = f >> 4, is = f & 15;
      *reinterpret_cast<float4*>(&As[kk][is * 4]) =
          *reinterpret_cast<const float4*>(&A[(size_t)(k0 + kk) * IDF + is * 4]);
    }
#pragma unroll
    for (int p = 0; p < 4; ++p) {            // W tile: transpose-stage
      int f = tid + p * 256;
      int oo = f >> 3, seg = f & 7;
      float4 v = *reinterpret_cast<const float4*>(
          &Wt[((size_t)h * SSZ + o_base + oo) * CDF + c0k + seg * 4]);
      Ws[seg * 4 + 0][oo] = v.x; Ws[seg * 4 + 1][oo] = v.y;
      Ws[seg * 4 + 2][oo] = v.z; Ws[seg * 4 + 3][oo] = v.w;
    }
    __syncthreads();
#pragma unroll
    for (int kq = 0; kq < 8; ++kq) {
#pragma unroll
      for (int kk = 0; kk < 4; ++kk) {
        int ko = kq * 4 + kk;
        float4 a0 = *reinterpret_cast<const float4*>(&As[ko][i0]);
        float4 a1 = *reinterpret_cast<const float4*>(&As[ko][i0 + 4]);
        float4 bv = *reinterpret_cast<const float4*>(&Ws[ko][o0]);
        float ar[8] = {a0.x, a0.y, a0.z, a0.w, a1.x, a1.y, a1.z, a1.w};
#pragma unroll
        for (int r = 0; r < 8; ++r) {
          acc[r][0] += ar[r] * bv.x; acc[r][1] += ar[r] * bv.y;
          acc[r][2] += ar[r] * bv.z; acc[r][3] += ar[r] * bv.w;
        }
      }
    }
    __syncthreads();
  }
#pragma unroll
  for (int r = 0; r < 8; ++r) {
    float4 v = {acc[r][0], acc[r][1], acc[r][2], acc[r][3]};
    *reinterpret_cast<float4*>(&outc[((size_t)b * IDF + i0 + r) * SSZ + o_base + o0]) = v;
  }
}

// ---------------------------------------------------------------------------
// K5: attn_out[b][l][i] = sum_h attn[bh][i][l]   (transpose + head-sum)
// ---------------------------------------------------------------------------
__global__ __launch_bounds__(256) void k_attnout(const float* __restrict__ attn,
                                                 float* __restrict__ outa) {
  __shared__ float T[64][65];
  int blk = blockIdx.x; int b = blk >> 2, lt = blk & 3;
  int l0 = lt * 64;
  int tid = threadIdx.x;
  float4 acc[4];
#pragma unroll
  for (int p = 0; p < 4; ++p) acc[p] = make_float4(0.f, 0.f, 0.f, 0.f);
  for (int h = 0; h < NH; ++h) {
    const float* src = attn + (size_t)(b * NH + h) * IDF * LL;
#pragma unroll
    for (int p = 0; p < 4; ++p) {
      int f = tid + p * 256;
      int i = f >> 4, lc = (f & 15) * 4;
      float4 v = *reinterpret_cast<const float4*>(&src[i * LL + l0 + lc]);
      acc[p].x += v.x; acc[p].y += v.y; acc[p].z += v.z; acc[p].w += v.w;
    }
  }
#pragma unroll
  for (int p = 0; p < 4; ++p) {
    int f = tid + p * 256;
    int i = f >> 4, lc = (f & 15) * 4;
    T[i][lc + 0] = acc[p].x; T[i][lc + 1] = acc[p].y;
    T[i][lc + 2] = acc[p].z; T[i][lc + 3] = acc[p].w;
  }
  __syncthreads();
#pragma unroll
  for (int p = 0; p < 4; ++p) {
    int f = tid + p * 256;
    int lr = f >> 4, ic = (f & 15) * 4;
    float4 v = {T[ic + 0][lr], T[ic + 1][lr], T[ic + 2][lr], T[ic + 3][lr]};
    *reinterpret_cast<float4*>(&outa[((size_t)b * LL + l0 + lr) * IDF + ic]) = v;
  }
}

// ---------------------------------------------------------------------------
extern "C" void kernel_launch(void* const* d_in, const int* in_sizes, int n_in,
                              void* d_out, int out_size, void* d_ws, size_t ws_size,
                              hipStream_t stream) {
  const float* wc  = (const float*)d_in[0];   // [32][64][1024]
  const float* ctx = (const float*)d_in[1];   // [32][256][256]
  const float* W   = (const float*)d_in[2];   // [8][1024][256]
  float* out = (float*)d_out;                  // ctx_out (2097152) ++ attn_out (524288)

  float* Mbuf = (float*)d_ws;                          // [256][64][256] = 4M floats
  float* Abuf = Mbuf + (size_t)BB * NH * IDF * CDF;    // attn [256][64][256] = 4M floats
  float* Nbuf = Mbuf;                                  // N reuses M's space (M dead after K2)

  k_gemm_M <<<BB * NH, 256, 0, stream>>>(wc, W, Mbuf);
  k_attn   <<<BB * NH, 256, 0, stream>>>(Mbuf, ctx, Abuf);
  k_N      <<<BB * NH, 256, 0, stream>>>(ctx, Abuf, Nbuf);
  k_ctxout <<<BB * 8, 256, 0, stream>>>(Nbuf, W, out);
  k_attnout<<<BB * 4, 256, 0, stream>>>(Abuf, out + (size_t)BB * IDF * SSZ);
}

// Round 2
// 364.652 us; speedup vs baseline: 1.4034x; 1.4034x over previous
//
#include <hip/hip_runtime.h>

#define BB 32
#define IDF 64
#define CDF 256
#define SSZ 1024
#define NH 8
#define LL 256
#define KHC 2048   // NH*CDF

// ---------------------------------------------------------------------------
// K1: M[bh][i][c] = sum_o wc[b][i][o] * W[h][o][c]     (64x256, K=1024)
// ---------------------------------------------------------------------------
__global__ __launch_bounds__(256) void k_gemm_M(const float* __restrict__ wc,
                                                const float* __restrict__ Wt,
                                                float* __restrict__ Mout) {
  __shared__ float As[IDF][32];   // [i][k]  k-contiguous
  __shared__ float Bs[32][CDF];   // [k][c]  c-contiguous
  int bh = blockIdx.x; int b = bh >> 3, h = bh & 7;
  const float* A  = wc + (size_t)b * IDF * SSZ;
  const float* Bm = Wt + (size_t)h * SSZ * CDF;
  int tid = threadIdx.x;
  int tc = tid & 31, ti = tid >> 5;
  int c0 = tc * 8, i0 = ti * 8;
  float acc[8][8];
#pragma unroll
  for (int r = 0; r < 8; ++r)
#pragma unroll
    for (int s = 0; s < 8; ++s) acc[r][s] = 0.f;

  for (int k0 = 0; k0 < SSZ; k0 += 32) {
#pragma unroll
    for (int p = 0; p < 2; ++p) {            // A tile: 64 rows x 8 f4
      int f = tid + p * 256;
      int row = f >> 3, seg = f & 7;
      *reinterpret_cast<float4*>(&As[row][seg * 4]) =
          *reinterpret_cast<const float4*>(&A[row * SSZ + k0 + seg * 4]);
    }
#pragma unroll
    for (int p = 0; p < 8; ++p) {            // B tile: 32 rows x 64 f4
      int f = tid + p * 256;
      int kk = f >> 6, cs = f & 63;
      *reinterpret_cast<float4*>(&Bs[kk][cs * 4]) =
          *reinterpret_cast<const float4*>(&Bm[(size_t)(k0 + kk) * CDF + cs * 4]);
    }
    __syncthreads();
#pragma unroll
    for (int kq = 0; kq < 8; ++kq) {
      float4 av[8];
#pragma unroll
      for (int r = 0; r < 8; ++r)
        av[r] = *reinterpret_cast<const float4*>(&As[i0 + r][kq * 4]);
#pragma unroll
      for (int kk = 0; kk < 4; ++kk) {
        float4 b0 = *reinterpret_cast<const float4*>(&Bs[kq * 4 + kk][c0]);
        float4 b1 = *reinterpret_cast<const float4*>(&Bs[kq * 4 + kk][c0 + 4]);
        float bv[8] = {b0.x, b0.y, b0.z, b0.w, b1.x, b1.y, b1.z, b1.w};
#pragma unroll
        for (int r = 0; r < 8; ++r) {
          float a = (kk == 0) ? av[r].x : (kk == 1) ? av[r].y : (kk == 2) ? av[r].z : av[r].w;
#pragma unroll
          for (int s = 0; s < 8; ++s) acc[r][s] += a * bv[s];
        }
      }
    }
    __syncthreads();
  }
  float* out = Mout + (size_t)bh * IDF * CDF;
#pragma unroll
  for (int r = 0; r < 8; ++r) {
    float4 v0 = {acc[r][0], acc[r][1], acc[r][2], acc[r][3]};
    float4 v1 = {acc[r][4], acc[r][5], acc[r][6], acc[r][7]};
    *reinterpret_cast<float4*>(&out[(i0 + r) * CDF + c0]) = v0;
    *reinterpret_cast<float4*>(&out[(i0 + r) * CDF + c0 + 4]) = v1;
  }
}

// ---------------------------------------------------------------------------
// K2: logits[bh][i][l] = sum_c M[bh][i][c] * ctx[b][c][l]; softmax over l
// ---------------------------------------------------------------------------
__global__ __launch_bounds__(256) void k_attn(const float* __restrict__ Mm,
                                              const float* __restrict__ ctx,
                                              float* __restrict__ attn) {
  __shared__ float As[IDF][32];
  __shared__ float Bs[32][LL];
  int bh = blockIdx.x; int b = bh >> 3;
  const float* A  = Mm + (size_t)bh * IDF * CDF;
  const float* Bm = ctx + (size_t)b * CDF * LL;
  int tid = threadIdx.x;
  int tc = tid & 31, ti = tid >> 5;
  int c0 = tc * 8, i0 = ti * 8;
  float acc[8][8];
#pragma unroll
  for (int r = 0; r < 8; ++r)
#pragma unroll
    for (int s = 0; s < 8; ++s) acc[r][s] = 0.f;

  for (int k0 = 0; k0 < CDF; k0 += 32) {
#pragma unroll
    for (int p = 0; p < 2; ++p) {
      int f = tid + p * 256;
      int row = f >> 3, seg = f & 7;
      *reinterpret_cast<float4*>(&As[row][seg * 4]) =
          *reinterpret_cast<const float4*>(&A[row * CDF + k0 + seg * 4]);
    }
#pragma unroll
    for (int p = 0; p < 8; ++p) {
      int f = tid + p * 256;
      int kk = f >> 6, cs = f & 63;
      *reinterpret_cast<float4*>(&Bs[kk][cs * 4]) =
          *reinterpret_cast<const float4*>(&Bm[(size_t)(k0 + kk) * LL + cs * 4]);
    }
    __syncthreads();
#pragma unroll
    for (int kq = 0; kq < 8; ++kq) {
      float4 av[8];
#pragma unroll
      for (int r = 0; r < 8; ++r)
        av[r] = *reinterpret_cast<const float4*>(&As[i0 + r][kq * 4]);
#pragma unroll
      for (int kk = 0; kk < 4; ++kk) {
        float4 b0 = *reinterpret_cast<const float4*>(&Bs[kq * 4 + kk][c0]);
        float4 b1 = *reinterpret_cast<const float4*>(&Bs[kq * 4 + kk][c0 + 4]);
        float bv[8] = {b0.x, b0.y, b0.z, b0.w, b1.x, b1.y, b1.z, b1.w};
#pragma unroll
        for (int r = 0; r < 8; ++r) {
          float a = (kk == 0) ? av[r].x : (kk == 1) ? av[r].y : (kk == 2) ? av[r].z : av[r].w;
#pragma unroll
          for (int s = 0; s < 8; ++s) acc[r][s] += a * bv[s];
        }
      }
    }
    __syncthreads();
  }
  float* out = attn + (size_t)bh * IDF * LL;
#pragma unroll
  for (int r = 0; r < 8; ++r) {
    float mx = acc[r][0];
#pragma unroll
    for (int s = 1; s < 8; ++s) mx = fmaxf(mx, acc[r][s]);
#pragma unroll
    for (int m = 16; m >= 1; m >>= 1) mx = fmaxf(mx, __shfl_xor(mx, m, 64));
    float ex[8]; float sum = 0.f;
#pragma unroll
    for (int s = 0; s < 8; ++s) { ex[s] = __expf(acc[r][s] - mx); sum += ex[s]; }
#pragma unroll
    for (int m = 16; m >= 1; m >>= 1) sum += __shfl_xor(sum, m, 64);
    float inv = 1.f / sum;
    float4 v0 = {ex[0] * inv, ex[1] * inv, ex[2] * inv, ex[3] * inv};
    float4 v1 = {ex[4] * inv, ex[5] * inv, ex[6] * inv, ex[7] * inv};
    *reinterpret_cast<float4*>(&out[(i0 + r) * LL + c0]) = v0;
    *reinterpret_cast<float4*>(&out[(i0 + r) * LL + c0 + 4]) = v1;
  }
}

// ---------------------------------------------------------------------------
// K3 (rewritten, K1-structure): N2[b][i][h*256+c] = sum_l attn[bh][i][l]*ctx[b][c][l]
// A = attn[bh] (l-contig rows). B = ctx^T, transpose-staged.  64x256, K=256.
// ---------------------------------------------------------------------------
__global__ __launch_bounds__(256) void k_N2(const float* __restrict__ attn,
                                            const float* __restrict__ ctx,
                                            float* __restrict__ N2) {
  __shared__ float As[IDF][32];    // [i][l]
  __shared__ float Bs[32][260];    // [l][c], padded
  int bh = blockIdx.x; int b = bh >> 3, h = bh & 7;
  const float* A  = attn + (size_t)bh * IDF * LL;
  const float* Cm = ctx + (size_t)b * CDF * LL;
  int tid = threadIdx.x;
  int tc = tid & 31, ti = tid >> 5;
  int c0 = tc * 8, i0 = ti * 8;
  float acc[8][8];
#pragma unroll
  for (int r = 0; r < 8; ++r)
#pragma unroll
    for (int s = 0; s < 8; ++s) acc[r][s] = 0.f;

  for (int l0 = 0; l0 < LL; l0 += 32) {
#pragma unroll
    for (int p = 0; p < 2; ++p) {            // attn tile: 64 rows x 8 f4
      int f = tid + p * 256;
      int row = f >> 3, seg = f & 7;
      *reinterpret_cast<float4*>(&As[row][seg * 4]) =
          *reinterpret_cast<const float4*>(&A[row * LL + l0 + seg * 4]);
    }
#pragma unroll
    for (int p = 0; p < 8; ++p) {            // ctx tile: transpose-stage [c][l]->[l][c]
      int f = tid + p * 256;
      int c = f >> 3, seg = f & 7;
      float4 v = *reinterpret_cast<const float4*>(&Cm[c * LL + l0 + seg * 4]);
      Bs[seg * 4 + 0][c] = v.x; Bs[seg * 4 + 1][c] = v.y;
      Bs[seg * 4 + 2][c] = v.z; Bs[seg * 4 + 3][c] = v.w;
    }
    __syncthreads();
#pragma unroll
    for (int kq = 0; kq < 8; ++kq) {
      float4 av[8];
#pragma unroll
      for (int r = 0; r < 8; ++r)
        av[r] = *reinterpret_cast<const float4*>(&As[i0 + r][kq * 4]);
#pragma unroll
      for (int kk = 0; kk < 4; ++kk) {
        float4 b0 = *reinterpret_cast<const float4*>(&Bs[kq * 4 + kk][c0]);
        float4 b1 = *reinterpret_cast<const float4*>(&Bs[kq * 4 + kk][c0 + 4]);
        float bv[8] = {b0.x, b0.y, b0.z, b0.w, b1.x, b1.y, b1.z, b1.w};
#pragma unroll
        for (int r = 0; r < 8; ++r) {
          float a = (kk == 0) ? av[r].x : (kk == 1) ? av[r].y : (kk == 2) ? av[r].z : av[r].w;
#pragma unroll
          for (int s = 0; s < 8; ++s) acc[r][s] += a * bv[s];
        }
      }
    }
    __syncthreads();
  }
  float* out = N2 + (size_t)b * IDF * KHC + h * CDF;
#pragma unroll
  for (int r = 0; r < 8; ++r) {
    float4 v0 = {acc[r][0], acc[r][1], acc[r][2], acc[r][3]};
    float4 v1 = {acc[r][4], acc[r][5], acc[r][6], acc[r][7]};
    *reinterpret_cast<float4*>(&out[(size_t)(i0 + r) * KHC + c0]) = v0;
    *reinterpret_cast<float4*>(&out[(size_t)(i0 + r) * KHC + c0 + 4]) = v1;
  }
}

// ---------------------------------------------------------------------------
// K4: ctx_out[b][i][o] = sum_{h,c} N2[b][i][hc] * W[h][o][c]
// Split K over 2 h-groups (g=0 -> d_out, g=1 -> P), 512 blocks = 2/CU.
// Per block: 64i x 128o, K = 1024.
// ---------------------------------------------------------------------------
__global__ __launch_bounds__(256) void k_ctxout(const float* __restrict__ N2,
                                                const float* __restrict__ Wt,
                                                float* __restrict__ out0,
                                                float* __restrict__ out1) {
  __shared__ float As[IDF][32];    // [i][k]
  __shared__ float Ws[32][132];    // [k(c)][o], transposed + padded
  int blk = blockIdx.x;
  int g = blk >> 8;                // 0..1 : h in {4g..4g+3}
  int r8 = blk & 255;
  int b = r8 >> 3, ot = r8 & 7;
  int obase = ot * 128;
  const float* A = N2 + (size_t)b * IDF * KHC;
  int tid = threadIdx.x;
  int tc = tid & 15, ti = tid >> 4;
  int o0 = tc * 8, i0 = ti * 4;
  float acc[4][8];
#pragma unroll
  for (int r = 0; r < 4; ++r)
#pragma unroll
    for (int s = 0; s < 8; ++s) acc[r][s] = 0.f;

  int kbase = g * (KHC / 2);
  for (int k0 = 0; k0 < KHC / 2; k0 += 32) {
    int kk0 = kbase + k0;
    int h = kk0 >> 8, cbase = kk0 & 255;
#pragma unroll
    for (int p = 0; p < 2; ++p) {            // N2 tile: 64 rows x 8 f4 (k-contig)
      int f = tid + p * 256;
      int row = f >> 3, seg = f & 7;
      *reinterpret_cast<float4*>(&As[row][seg * 4]) =
          *reinterpret_cast<const float4*>(&A[(size_t)row * KHC + kk0 + seg * 4]);
    }
#pragma unroll
    for (int p = 0; p < 4; ++p) {            // W tile: transpose-stage [o][c]->[c][o]
      int f = tid + p * 256;
      int oo = f >> 3, seg = f & 7;
      float4 v = *reinterpret_cast<const float4*>(
          &Wt[((size_t)h * SSZ + obase + oo) * CDF + cbase + seg * 4]);
      Ws[seg * 4 + 0][oo] = v.x; Ws[seg * 4 + 1][oo] = v.y;
      Ws[seg * 4 + 2][oo] = v.z; Ws[seg * 4 + 3][oo] = v.w;
    }
    __syncthreads();
#pragma unroll
    for (int kq = 0; kq < 8; ++kq) {
      float4 av[4];
#pragma unroll
      for (int r = 0; r < 4; ++r)
        av[r] = *reinterpret_cast<const float4*>(&As[i0 + r][kq * 4]);
#pragma unroll
      for (int kk = 0; kk < 4; ++kk) {
        float4 b0 = *reinterpret_cast<const float4*>(&Ws[kq * 4 + kk][o0]);
        float4 b1 = *reinterpret_cast<const float4*>(&Ws[kq * 4 + kk][o0 + 4]);
        float bv[8] = {b0.x, b0.y, b0.z, b0.w, b1.x, b1.y, b1.z, b1.w};
#pragma unroll
        for (int r = 0; r < 4; ++r) {
          float a = (kk == 0) ? av[r].x : (kk == 1) ? av[r].y : (kk == 2) ? av[r].z : av[r].w;
#pragma unroll
          for (int s = 0; s < 8; ++s) acc[r][s] += a * bv[s];
        }
      }
    }
    __syncthreads();
  }
  float* dst = (g == 0) ? out0 : out1;
#pragma unroll
  for (int r = 0; r < 4; ++r) {
    float4 v0 = {acc[r][0], acc[r][1], acc[r][2], acc[r][3]};
    float4 v1 = {acc[r][4], acc[r][5], acc[r][6], acc[r][7]};
    size_t base = ((size_t)b * IDF + i0 + r) * SSZ + obase + o0;
    *reinterpret_cast<float4*>(&dst[base]) = v0;
    *reinterpret_cast<float4*>(&dst[base + 4]) = v1;
  }
}

// out += P  (fold g1 partial into final output)
__global__ __launch_bounds__(256) void k_add(float* __restrict__ out,
                                             const float* __restrict__ P) {
  int idx = blockIdx.x * 256 + threadIdx.x;
  float4 a = reinterpret_cast<float4*>(out)[idx];
  float4 p = reinterpret_cast<const float4*>(P)[idx];
  a.x += p.x; a.y += p.y; a.z += p.z; a.w += p.w;
  reinterpret_cast<float4*>(out)[idx] = a;
}

// ---------------------------------------------------------------------------
// K5: attn_out[b][l][i] = sum_h attn[bh][i][l]   (transpose + head-sum)
// ---------------------------------------------------------------------------
__global__ __launch_bounds__(256) void k_attnout(const float* __restrict__ attn,
                                                 float* __restrict__ outa) {
  __shared__ float T[64][65];
  int blk = blockIdx.x; int b = blk >> 2, lt = blk & 3;
  int l0 = lt * 64;
  int tid = threadIdx.x;
  float4 acc[4];
#pragma unroll
  for (int p = 0; p < 4; ++p) acc[p] = make_float4(0.f, 0.f, 0.f, 0.f);
  for (int h = 0; h < NH; ++h) {
    const float* src = attn + (size_t)(b * NH + h) * IDF * LL;
#pragma unroll
    for (int p = 0; p < 4; ++p) {
      int f = tid + p * 256;
      int i = f >> 4, lc = (f & 15) * 4;
      float4 v = *reinterpret_cast<const float4*>(&src[i * LL + l0 + lc]);
      acc[p].x += v.x; acc[p].y += v.y; acc[p].z += v.z; acc[p].w += v.w;
    }
  }
#pragma unroll
  for (int p = 0; p < 4; ++p) {
    int f = tid + p * 256;
    int i = f >> 4, lc = (f & 15) * 4;
    T[i][lc + 0] = acc[p].x; T[i][lc + 1] = acc[p].y;
    T[i][lc + 2] = acc[p].z; T[i][lc + 3] = acc[p].w;
  }
  __syncthreads();
#pragma unroll
  for (int p = 0; p < 4; ++p) {
    int f = tid + p * 256;
    int lr = f >> 4, ic = (f & 15) * 4;
    float4 v = {T[ic + 0][lr], T[ic + 1][lr], T[ic + 2][lr], T[ic + 3][lr]};
    *reinterpret_cast<float4*>(&outa[((size_t)b * LL + l0 + lr) * IDF + ic]) = v;
  }
}

// ---------------------------------------------------------------------------
extern "C" void kernel_launch(void* const* d_in, const int* in_sizes, int n_in,
                              void* d_out, int out_size, void* d_ws, size_t ws_size,
                              hipStream_t stream) {
  const float* wc  = (const float*)d_in[0];   // [32][64][1024]
  const float* ctx = (const float*)d_in[1];   // [32][256][256]
  const float* W   = (const float*)d_in[2];   // [8][1024][256]
  float* out = (float*)d_out;                  // ctx_out (2097152) ++ attn_out (524288)

  float* Mbuf = (float*)d_ws;                          // 4.19M floats (16.8MB)
  float* Abuf = Mbuf + (size_t)BB * NH * IDF * CDF;    // attn, 4.19M floats
  float* Nbuf = Mbuf;                                  // N2 reuses M (M dead after K2)
  float* Pbuf = Abuf;                                  // K4 g1 partial reuses attn
                                                       // (attn dead after k_attnout)

  k_gemm_M <<<BB * NH, 256, 0, stream>>>(wc, W, Mbuf);
  k_attn   <<<BB * NH, 256, 0, stream>>>(Mbuf, ctx, Abuf);
  k_N2     <<<BB * NH, 256, 0, stream>>>(Abuf, ctx, Nbuf);
  k_attnout<<<BB * 4, 256, 0, stream>>>(Abuf, out + (size_t)BB * IDF * SSZ);
  k_ctxout <<<512, 256, 0, stream>>>(Nbuf, W, out, Pbuf);
  k_add    <<<2048, 256, 0, stream>>>(out, Pbuf);
}

// Round 3
// 327.628 us; speedup vs baseline: 1.5620x; 1.1130x over previous
//
#include <hip/hip_runtime.h>
#include <hip/hip_bf16.h>

#define BB 32
#define IDF 64
#define CDF 256
#define SSZ 1024
#define NH 8
#define LL 256
#define KHC 2048   // NH*CDF

typedef __attribute__((ext_vector_type(8))) short short8v;   // 8 bf16 (4 VGPR)
typedef __attribute__((ext_vector_type(4))) float f32x4;     // MFMA acc

// ---------------------------------------------------------------------------
// Split wc (fp32) -> wch, wcl (bf16 hi/lo), same [b][i][o] layout.
// ---------------------------------------------------------------------------
__global__ __launch_bounds__(256) void k_split_wc(const float* __restrict__ wc,
                                                  __hip_bfloat16* __restrict__ wch,
                                                  __hip_bfloat16* __restrict__ wcl) {
  int idx = (blockIdx.x * 256 + threadIdx.x) * 4;
  float4 v = *reinterpret_cast<const float4*>(&wc[idx]);
  __hip_bfloat16 h0 = __float2bfloat16(v.x), h1 = __float2bfloat16(v.y);
  __hip_bfloat16 h2 = __float2bfloat16(v.z), h3 = __float2bfloat16(v.w);
  __hip_bfloat16 l0 = __float2bfloat16(v.x - __bfloat162float(h0));
  __hip_bfloat16 l1 = __float2bfloat16(v.y - __bfloat162float(h1));
  __hip_bfloat16 l2 = __float2bfloat16(v.z - __bfloat162float(h2));
  __hip_bfloat16 l3 = __float2bfloat16(v.w - __bfloat162float(h3));
  wch[idx] = h0; wch[idx+1] = h1; wch[idx+2] = h2; wch[idx+3] = h3;
  wcl[idx] = l0; wcl[idx+1] = l1; wcl[idx+2] = l2; wcl[idx+3] = l3;
}

// ---------------------------------------------------------------------------
// Split+transpose W[h][o][c] (fp32) -> Wt hi/lo [h][c][o] (bf16).
// 64x64 tiles. grid = h(8) * otile(16) * ctile(4) = 512.
// ---------------------------------------------------------------------------
__global__ __launch_bounds__(256) void k_split_Wt(const float* __restrict__ W,
                                                  __hip_bfloat16* __restrict__ wth,
                                                  __hip_bfloat16* __restrict__ wtl) {
  __shared__ float Tt[64][65];   // [c][o]
  int blk = blockIdx.x;
  int h = blk >> 6, ot = (blk >> 2) & 15, ct = blk & 3;
  int og = ot * 64, cg = ct * 64;
  int t = threadIdx.x;
  int o_l = t >> 4, c4 = (t & 15) * 4;
#pragma unroll
  for (int p = 0; p < 4; ++p) {
    int o = o_l + 16 * p;
    float4 v = *reinterpret_cast<const float4*>(
        &W[((size_t)h * SSZ + og + o) * CDF + cg + c4]);
    Tt[c4 + 0][o] = v.x; Tt[c4 + 1][o] = v.y;
    Tt[c4 + 2][o] = v.z; Tt[c4 + 3][o] = v.w;
  }
  __syncthreads();
  int c_l = t >> 2;
#pragma unroll
  for (int p = 0; p < 4; ++p) {
    int oq = (t & 3) + 4 * p;
    int o0 = oq * 4;
    __hip_bfloat16 hv[4], lv[4];
#pragma unroll
    for (int j = 0; j < 4; ++j) {
      float x = Tt[c_l][o0 + j];
      hv[j] = __float2bfloat16(x);
      lv[j] = __float2bfloat16(x - __bfloat162float(hv[j]));
    }
    size_t base = ((size_t)h * CDF + cg + c_l) * SSZ + og + o0;
#pragma unroll
    for (int j = 0; j < 4; ++j) { wth[base + j] = hv[j]; wtl[base + j] = lv[j]; }
  }
}

// ---------------------------------------------------------------------------
// K1 (MFMA): M[bh][i][c] = sum_o wc[b][i][o] * W[h][o][c]
// NT bf16-split GEMM: A = wc hi/lo [i][o], B = Wt hi/lo [c][o]. 64x256, K=1024.
// 4 waves, each 64 rows x 64 cols = 4x4 frags of 16x16x32. kstep=32.
// ---------------------------------------------------------------------------
__global__ __launch_bounds__(256) void k1_mfma(const __hip_bfloat16* __restrict__ wch,
                                               const __hip_bfloat16* __restrict__ wcl,
                                               const __hip_bfloat16* __restrict__ wth,
                                               const __hip_bfloat16* __restrict__ wtl,
                                               float* __restrict__ Mout) {
  __shared__ __align__(16) short Ah[IDF * 32];
  __shared__ __align__(16) short Al[IDF * 32];
  __shared__ __align__(16) short Bh[CDF * 32];
  __shared__ __align__(16) short Bl[CDF * 32];

  int bh = blockIdx.x; int b = bh >> 3, h = bh & 7;
  int t = threadIdx.x;
  int lane = t & 63, wave = t >> 6;
  int ln15 = lane & 15, kh = lane >> 4;

  // staging decomposition: thread t covers row rA, 16B chunk qA
  int rA = t >> 2, qA = t & 3;
  int s = (rA >> 1) & 3;           // chunk swizzle for this row
  int qs = qA ^ s;                 // LDS chunk index for this thread's data

  const short* gA_h = (const short*)wch + ((size_t)b * IDF + rA) * SSZ;
  const short* gA_l = (const short*)wcl + ((size_t)b * IDF + rA) * SSZ;
  const short* gB_h = (const short*)wth + ((size_t)h * CDF) * SSZ;
  const short* gB_l = (const short*)wtl + ((size_t)h * CDF) * SSZ;

  f32x4 acc[4][4] = {};

  // fragment read offsets (shorts), constant across k-steps
  int offA[4], offB[4];
#pragma unroll
  for (int r = 0; r < 4; ++r) {
    int row = r * 16 + ln15;
    offA[r] = row * 32 + ((kh ^ ((row >> 1) & 3)) * 8);
  }
#pragma unroll
  for (int c = 0; c < 4; ++c) {
    int row = wave * 64 + c * 16 + ln15;
    offB[c] = row * 32 + ((kh ^ ((row >> 1) & 3)) * 8);
  }

#pragma unroll 1
  for (int k0 = 0; k0 < SSZ; k0 += 32) {
    // ---- global -> regs (A: 2 chunks, B: 8 chunks per thread)
    int4 va_h = *reinterpret_cast<const int4*>(&gA_h[k0 + qA * 8]);
    int4 va_l = *reinterpret_cast<const int4*>(&gA_l[k0 + qA * 8]);
    int4 vb_h[4], vb_l[4];
#pragma unroll
    for (int j = 0; j < 4; ++j) {
      size_t ga = (size_t)(j * 64 + rA) * SSZ + k0 + qA * 8;
      vb_h[j] = *reinterpret_cast<const int4*>(&gB_h[ga]);
      vb_l[j] = *reinterpret_cast<const int4*>(&gB_l[ga]);
    }
    __syncthreads();   // previous iteration's readers done
    // ---- regs -> LDS (chunk-swizzled)
    *reinterpret_cast<int4*>(&Ah[rA * 32 + qs * 8]) = va_h;
    *reinterpret_cast<int4*>(&Al[rA * 32 + qs * 8]) = va_l;
#pragma unroll
    for (int j = 0; j < 4; ++j) {
      *reinterpret_cast<int4*>(&Bh[(j * 64 + rA) * 32 + qs * 8]) = vb_h[j];
      *reinterpret_cast<int4*>(&Bl[(j * 64 + rA) * 32 + qs * 8]) = vb_l[j];
    }
    __syncthreads();
    // ---- fragments + MFMA
    short8v fa_h[4], fa_l[4], fb_h[4], fb_l[4];
#pragma unroll
    for (int r = 0; r < 4; ++r) {
      fa_h[r] = *reinterpret_cast<const short8v*>(&Ah[offA[r]]);
      fa_l[r] = *reinterpret_cast<const short8v*>(&Al[offA[r]]);
    }
#pragma unroll
    for (int c = 0; c < 4; ++c) {
      fb_h[c] = *reinterpret_cast<const short8v*>(&Bh[offB[c]]);
      fb_l[c] = *reinterpret_cast<const short8v*>(&Bl[offB[c]]);
    }
#pragma unroll
    for (int r = 0; r < 4; ++r)
#pragma unroll
      for (int c = 0; c < 4; ++c) {
        acc[r][c] = __builtin_amdgcn_mfma_f32_16x16x32_bf16(fa_h[r], fb_h[c], acc[r][c], 0, 0, 0);
        acc[r][c] = __builtin_amdgcn_mfma_f32_16x16x32_bf16(fa_h[r], fb_l[c], acc[r][c], 0, 0, 0);
        acc[r][c] = __builtin_amdgcn_mfma_f32_16x16x32_bf16(fa_l[r], fb_h[c], acc[r][c], 0, 0, 0);
      }
  }

  // ---- epilogue: D layout col=lane&15, row=(lane>>4)*4+reg
  float* out = Mout + (size_t)bh * IDF * CDF;
  int rowq = (lane >> 4) * 4;
  int colb = wave * 64 + ln15;
#pragma unroll
  for (int r = 0; r < 4; ++r)
#pragma unroll
    for (int c = 0; c < 4; ++c)
#pragma unroll
      for (int reg = 0; reg < 4; ++reg)
        out[(r * 16 + rowq + reg) * CDF + colb + c * 16] = acc[r][c][reg];
}

// ---------------------------------------------------------------------------
// K2: logits[bh][i][l] = sum_c M[bh][i][c] * ctx[b][c][l]; softmax over l
// ---------------------------------------------------------------------------
__global__ __launch_bounds__(256) void k_attn(const float* __restrict__ Mm,
                                              const float* __restrict__ ctx,
                                              float* __restrict__ attn) {
  __shared__ float As[IDF][32];
  __shared__ float Bs[32][LL];
  int bh = blockIdx.x; int b = bh >> 3;
  const float* A  = Mm + (size_t)bh * IDF * CDF;
  const float* Bm = ctx + (size_t)b * CDF * LL;
  int tid = threadIdx.x;
  int tc = tid & 31, ti = tid >> 5;
  int c0 = tc * 8, i0 = ti * 8;
  float acc[8][8];
#pragma unroll
  for (int r = 0; r < 8; ++r)
#pragma unroll
    for (int s = 0; s < 8; ++s) acc[r][s] = 0.f;

  for (int k0 = 0; k0 < CDF; k0 += 32) {
#pragma unroll
    for (int p = 0; p < 2; ++p) {
      int f = tid + p * 256;
      int row = f >> 3, seg = f & 7;
      *reinterpret_cast<float4*>(&As[row][seg * 4]) =
          *reinterpret_cast<const float4*>(&A[row * CDF + k0 + seg * 4]);
    }
#pragma unroll
    for (int p = 0; p < 8; ++p) {
      int f = tid + p * 256;
      int kk = f >> 6, cs = f & 63;
      *reinterpret_cast<float4*>(&Bs[kk][cs * 4]) =
          *reinterpret_cast<const float4*>(&Bm[(size_t)(k0 + kk) * LL + cs * 4]);
    }
    __syncthreads();
#pragma unroll
    for (int kq = 0; kq < 8; ++kq) {
      float4 av[8];
#pragma unroll
      for (int r = 0; r < 8; ++r)
        av[r] = *reinterpret_cast<const float4*>(&As[i0 + r][kq * 4]);
#pragma unroll
      for (int kk = 0; kk < 4; ++kk) {
        float4 b0 = *reinterpret_cast<const float4*>(&Bs[kq * 4 + kk][c0]);
        float4 b1 = *reinterpret_cast<const float4*>(&Bs[kq * 4 + kk][c0 + 4]);
        float bv[8] = {b0.x, b0.y, b0.z, b0.w, b1.x, b1.y, b1.z, b1.w};
#pragma unroll
        for (int r = 0; r < 8; ++r) {
          float a = (kk == 0) ? av[r].x : (kk == 1) ? av[r].y : (kk == 2) ? av[r].z : av[r].w;
#pragma unroll
          for (int s = 0; s < 8; ++s) acc[r][s] += a * bv[s];
        }
      }
    }
    __syncthreads();
  }
  float* out = attn + (size_t)bh * IDF * LL;
#pragma unroll
  for (int r = 0; r < 8; ++r) {
    float mx = acc[r][0];
#pragma unroll
    for (int s = 1; s < 8; ++s) mx = fmaxf(mx, acc[r][s]);
#pragma unroll
    for (int m = 16; m >= 1; m >>= 1) mx = fmaxf(mx, __shfl_xor(mx, m, 64));
    float ex[8]; float sum = 0.f;
#pragma unroll
    for (int s = 0; s < 8; ++s) { ex[s] = __expf(acc[r][s] - mx); sum += ex[s]; }
#pragma unroll
    for (int m = 16; m >= 1; m >>= 1) sum += __shfl_xor(sum, m, 64);
    float inv = 1.f / sum;
    float4 v0 = {ex[0] * inv, ex[1] * inv, ex[2] * inv, ex[3] * inv};
    float4 v1 = {ex[4] * inv, ex[5] * inv, ex[6] * inv, ex[7] * inv};
    *reinterpret_cast<float4*>(&out[(i0 + r) * LL + c0]) = v0;
    *reinterpret_cast<float4*>(&out[(i0 + r) * LL + c0 + 4]) = v1;
  }
}

// ---------------------------------------------------------------------------
// K3: N2[b][i][h*256+c] = sum_l attn[bh][i][l]*ctx[b][c][l]
// ---------------------------------------------------------------------------
__global__ __launch_bounds__(256) void k_N2(const float* __restrict__ attn,
                                            const float* __restrict__ ctx,
                                            float* __restrict__ N2) {
  __shared__ float As[IDF][32];    // [i][l]
  __shared__ float Bs[32][260];    // [l][c], padded
  int bh = blockIdx.x; int b = bh >> 3, h = bh & 7;
  const float* A  = attn + (size_t)bh * IDF * LL;
  const float* Cm = ctx + (size_t)b * CDF * LL;
  int tid = threadIdx.x;
  int tc = tid & 31, ti = tid >> 5;
  int c0 = tc * 8, i0 = ti * 8;
  float acc[8][8];
#pragma unroll
  for (int r = 0; r < 8; ++r)
#pragma unroll
    for (int s = 0; s < 8; ++s) acc[r][s] = 0.f;

  for (int l0 = 0; l0 < LL; l0 += 32) {
#pragma unroll
    for (int p = 0; p < 2; ++p) {
      int f = tid + p * 256;
      int row = f >> 3, seg = f & 7;
      *reinterpret_cast<float4*>(&As[row][seg * 4]) =
          *reinterpret_cast<const float4*>(&A[row * LL + l0 + seg * 4]);
    }
#pragma unroll
    for (int p = 0; p < 8; ++p) {
      int f = tid + p * 256;
      int c = f >> 3, seg = f & 7;
      float4 v = *reinterpret_cast<const float4*>(&Cm[c * LL + l0 + seg * 4]);
      Bs[seg * 4 + 0][c] = v.x; Bs[seg * 4 + 1][c] = v.y;
      Bs[seg * 4 + 2][c] = v.z; Bs[seg * 4 + 3][c] = v.w;
    }
    __syncthreads();
#pragma unroll
    for (int kq = 0; kq < 8; ++kq) {
      float4 av[8];
#pragma unroll
      for (int r = 0; r < 8; ++r)
        av[r] = *reinterpret_cast<const float4*>(&As[i0 + r][kq * 4]);
#pragma unroll
      for (int kk = 0; kk < 4; ++kk) {
        float4 b0 = *reinterpret_cast<const float4*>(&Bs[kq * 4 + kk][c0]);
        float4 b1 = *reinterpret_cast<const float4*>(&Bs[kq * 4 + kk][c0 + 4]);
        float bv[8] = {b0.x, b0.y, b0.z, b0.w, b1.x, b1.y, b1.z, b1.w};
#pragma unroll
        for (int r = 0; r < 8; ++r) {
          float a = (kk == 0) ? av[r].x : (kk == 1) ? av[r].y : (kk == 2) ? av[r].z : av[r].w;
#pragma unroll
          for (int s = 0; s < 8; ++s) acc[r][s] += a * bv[s];
        }
      }
    }
    __syncthreads();
  }
  float* out = N2 + (size_t)b * IDF * KHC + h * CDF;
#pragma unroll
  for (int r = 0; r < 8; ++r) {
    float4 v0 = {acc[r][0], acc[r][1], acc[r][2], acc[r][3]};
    float4 v1 = {acc[r][4], acc[r][5], acc[r][6], acc[r][7]};
    *reinterpret_cast<float4*>(&out[(size_t)(i0 + r) * KHC + c0]) = v0;
    *reinterpret_cast<float4*>(&out[(size_t)(i0 + r) * KHC + c0 + 4]) = v1;
  }
}

// ---------------------------------------------------------------------------
// K4: ctx_out[b][i][o] = sum_{h,c} N2[b][i][hc] * W[h][o][c]
// ---------------------------------------------------------------------------
__global__ __launch_bounds__(256) void k_ctxout(const float* __restrict__ N2,
                                                const float* __restrict__ Wt,
                                                float* __restrict__ out0,
                                                float* __restrict__ out1) {
  __shared__ float As[IDF][32];    // [i][k]
  __shared__ float Ws[32][132];    // [k(c)][o], transposed + padded
  int blk = blockIdx.x;
  int g = blk >> 8;
  int r8 = blk & 255;
  int b = r8 >> 3, ot = r8 & 7;
  int obase = ot * 128;
  const float* A = N2 + (size_t)b * IDF * KHC;
  int tid = threadIdx.x;
  int tc = tid & 15, ti = tid >> 4;
  int o0 = tc * 8, i0 = ti * 4;
  float acc[4][8];
#pragma unroll
  for (int r = 0; r < 4; ++r)
#pragma unroll
    for (int s = 0; s < 8; ++s) acc[r][s] = 0.f;

  int kbase = g * (KHC / 2);
  for (int k0 = 0; k0 < KHC / 2; k0 += 32) {
    int kk0 = kbase + k0;
    int h = kk0 >> 8, cbase = kk0 & 255;
#pragma unroll
    for (int p = 0; p < 2; ++p) {
      int f = tid + p * 256;
      int row = f >> 3, seg = f & 7;
      *reinterpret_cast<float4*>(&As[row][seg * 4]) =
          *reinterpret_cast<const float4*>(&A[(size_t)row * KHC + kk0 + seg * 4]);
    }
#pragma unroll
    for (int p = 0; p < 4; ++p) {
      int f = tid + p * 256;
      int oo = f >> 3, seg = f & 7;
      float4 v = *reinterpret_cast<const float4*>(
          &Wt[((size_t)h * SSZ + obase + oo) * CDF + cbase + seg * 4]);
      Ws[seg * 4 + 0][oo] = v.x; Ws[seg * 4 + 1][oo] = v.y;
      Ws[seg * 4 + 2][oo] = v.z; Ws[seg * 4 + 3][oo] = v.w;
    }
    __syncthreads();
#pragma unroll
    for (int kq = 0; kq < 8; ++kq) {
      float4 av[4];
#pragma unroll
      for (int r = 0; r < 4; ++r)
        av[r] = *reinterpret_cast<const float4*>(&As[i0 + r][kq * 4]);
#pragma unroll
      for (int kk = 0; kk < 4; ++kk) {
        float4 b0 = *reinterpret_cast<const float4*>(&Ws[kq * 4 + kk][o0]);
        float4 b1 = *reinterpret_cast<const float4*>(&Ws[kq * 4 + kk][o0 + 4]);
        float bv[8] = {b0.x, b0.y, b0.z, b0.w, b1.x, b1.y, b1.z, b1.w};
#pragma unroll
        for (int r = 0; r < 4; ++r) {
          float a = (kk == 0) ? av[r].x : (kk == 1) ? av[r].y : (kk == 2) ? av[r].z : av[r].w;
#pragma unroll
          for (int s = 0; s < 8; ++s) acc[r][s] += a * bv[s];
        }
      }
    }
    __syncthreads();
  }
  float* dst = (g == 0) ? out0 : out1;
#pragma unroll
  for (int r = 0; r < 4; ++r) {
    float4 v0 = {acc[r][0], acc[r][1], acc[r][2], acc[r][3]};
    float4 v1 = {acc[r][4], acc[r][5], acc[r][6], acc[r][7]};
    size_t base = ((size_t)b * IDF + i0 + r) * SSZ + obase + o0;
    *reinterpret_cast<float4*>(&dst[base]) = v0;
    *reinterpret_cast<float4*>(&dst[base + 4]) = v1;
  }
}

// out += P
__global__ __launch_bounds__(256) void k_add(float* __restrict__ out,
                                             const float* __restrict__ P) {
  int idx = blockIdx.x * 256 + threadIdx.x;
  float4 a = reinterpret_cast<float4*>(out)[idx];
  float4 p = reinterpret_cast<const float4*>(P)[idx];
  a.x += p.x; a.y += p.y; a.z += p.z; a.w += p.w;
  reinterpret_cast<float4*>(out)[idx] = a;
}

// ---------------------------------------------------------------------------
// K5: attn_out[b][l][i] = sum_h attn[bh][i][l]
// ---------------------------------------------------------------------------
__global__ __launch_bounds__(256) void k_attnout(const float* __restrict__ attn,
                                                 float* __restrict__ outa) {
  __shared__ float T[64][65];
  int blk = blockIdx.x; int b = blk >> 2, lt = blk & 3;
  int l0 = lt * 64;
  int tid = threadIdx.x;
  float4 acc[4];
#pragma unroll
  for (int p = 0; p < 4; ++p) acc[p] = make_float4(0.f, 0.f, 0.f, 0.f);
  for (int h = 0; h < NH; ++h) {
    const float* src = attn + (size_t)(b * NH + h) * IDF * LL;
#pragma unroll
    for (int p = 0; p < 4; ++p) {
      int f = tid + p * 256;
      int i = f >> 4, lc = (f & 15) * 4;
      float4 v = *reinterpret_cast<const float4*>(&src[i * LL + l0 + lc]);
      acc[p].x += v.x; acc[p].y += v.y; acc[p].z += v.z; acc[p].w += v.w;
    }
  }
#pragma unroll
  for (int p = 0; p < 4; ++p) {
    int f = tid + p * 256;
    int i = f >> 4, lc = (f & 15) * 4;
    T[i][lc + 0] = acc[p].x; T[i][lc + 1] = acc[p].y;
    T[i][lc + 2] = acc[p].z; T[i][lc + 3] = acc[p].w;
  }
  __syncthreads();
#pragma unroll
  for (int p = 0; p < 4; ++p) {
    int f = tid + p * 256;
    int lr = f >> 4, ic = (f & 15) * 4;
    float4 v = {T[ic + 0][lr], T[ic + 1][lr], T[ic + 2][lr], T[ic + 3][lr]};
    *reinterpret_cast<float4*>(&outa[((size_t)b * LL + l0 + lr) * IDF + ic]) = v;
  }
}

// ---------------------------------------------------------------------------
extern "C" void kernel_launch(void* const* d_in, const int* in_sizes, int n_in,
                              void* d_out, int out_size, void* d_ws, size_t ws_size,
                              hipStream_t stream) {
  const float* wc  = (const float*)d_in[0];   // [32][64][1024]
  const float* ctx = (const float*)d_in[1];   // [32][256][256]
  const float* W   = (const float*)d_in[2];   // [8][1024][256]
  float* out = (float*)d_out;

  float* Mbuf = (float*)d_ws;                          // 4.19M floats
  float* Abuf = Mbuf + (size_t)BB * NH * IDF * CDF;    // attn region, 4.19M floats
  float* Nbuf = Mbuf;                                  // N2 reuses M
  float* Pbuf = Abuf;                                  // K4 g1 partial reuses attn

  // bf16 split buffers live inside Abuf (dead until k_attn writes it)
  __hip_bfloat16* wch = (__hip_bfloat16*)Abuf;             // 2M bf16
  __hip_bfloat16* wcl = wch + (size_t)BB * IDF * SSZ;      // 2M
  __hip_bfloat16* wth = wcl + (size_t)BB * IDF * SSZ;      // 2M
  __hip_bfloat16* wtl = wth + (size_t)NH * CDF * SSZ;      // 2M  (16 MB total)

  k_split_wc<<<2048, 256, 0, stream>>>(wc, wch, wcl);
  k_split_Wt<<<512, 256, 0, stream>>>(W, wth, wtl);
  k1_mfma   <<<BB * NH, 256, 0, stream>>>(wch, wcl, wth, wtl, Mbuf);
  k_attn    <<<BB * NH, 256, 0, stream>>>(Mbuf, ctx, Abuf);
  k_N2      <<<BB * NH, 256, 0, stream>>>(Abuf, ctx, Nbuf);
  k_attnout <<<BB * 4, 256, 0, stream>>>(Abuf, out + (size_t)BB * IDF * SSZ);
  k_ctxout  <<<512, 256, 0, stream>>>(Nbuf, W, out, Pbuf);
  k_add     <<<2048, 256, 0, stream>>>(out, Pbuf);
}

// Round 4
// 297.240 us; speedup vs baseline: 1.7217x; 1.1022x over previous
//
#include <hip/hip_runtime.h>
#include <hip/hip_bf16.h>

#define BB 32
#define IDF 64
#define CDF 256
#define SSZ 1024
#define NH 8
#define LL 256
#define KHC 2048   // NH*CDF

typedef __attribute__((ext_vector_type(8))) short short8v;   // 8 bf16 (4 VGPR)
typedef __attribute__((ext_vector_type(4))) float f32x4;     // MFMA acc

__device__ inline void split_bf16(float x, __hip_bfloat16& h, __hip_bfloat16& l) {
  h = __float2bfloat16(x);
  l = __float2bfloat16(x - __bfloat162float(h));
}

// ---------------------------------------------------------------------------
// Split wc (fp32) -> wch, wcl (bf16 hi/lo), same [b][i][o] layout.
// ---------------------------------------------------------------------------
__global__ __launch_bounds__(256) void k_split_wc(const float* __restrict__ wc,
                                                  __hip_bfloat16* __restrict__ wch,
                                                  __hip_bfloat16* __restrict__ wcl) {
  int idx = (blockIdx.x * 256 + threadIdx.x) * 4;
  float4 v = *reinterpret_cast<const float4*>(&wc[idx]);
  __align__(16) __hip_bfloat16 hb[4], lb[4];
  split_bf16(v.x, hb[0], lb[0]); split_bf16(v.y, hb[1], lb[1]);
  split_bf16(v.z, hb[2], lb[2]); split_bf16(v.w, hb[3], lb[3]);
  *reinterpret_cast<int2*>(&wch[idx]) = *reinterpret_cast<int2*>(hb);
  *reinterpret_cast<int2*>(&wcl[idx]) = *reinterpret_cast<int2*>(lb);
}

// ---------------------------------------------------------------------------
// Split W (fp32, [h][o][c]) -> Wh, Wl (bf16, same layout). For K4.
// ---------------------------------------------------------------------------
__global__ __launch_bounds__(256) void k_split_W(const float* __restrict__ W,
                                                 __hip_bfloat16* __restrict__ Wh,
                                                 __hip_bfloat16* __restrict__ Wl) {
  int idx = (blockIdx.x * 256 + threadIdx.x) * 4;
  float4 v = *reinterpret_cast<const float4*>(&W[idx]);
  __align__(16) __hip_bfloat16 hb[4], lb[4];
  split_bf16(v.x, hb[0], lb[0]); split_bf16(v.y, hb[1], lb[1]);
  split_bf16(v.z, hb[2], lb[2]); split_bf16(v.w, hb[3], lb[3]);
  *reinterpret_cast<int2*>(&Wh[idx]) = *reinterpret_cast<int2*>(hb);
  *reinterpret_cast<int2*>(&Wl[idx]) = *reinterpret_cast<int2*>(lb);
}

// ---------------------------------------------------------------------------
// Split+transpose W[h][o][c] (fp32) -> Wt hi/lo [h][c][o] (bf16). For K1.
// ---------------------------------------------------------------------------
__global__ __launch_bounds__(256) void k_split_Wt(const float* __restrict__ W,
                                                  __hip_bfloat16* __restrict__ wth,
                                                  __hip_bfloat16* __restrict__ wtl) {
  __shared__ float Tt[64][65];   // [c][o]
  int blk = blockIdx.x;
  int h = blk >> 6, ot = (blk >> 2) & 15, ct = blk & 3;
  int og = ot * 64, cg = ct * 64;
  int t = threadIdx.x;
  int o_l = t >> 4, c4 = (t & 15) * 4;
#pragma unroll
  for (int p = 0; p < 4; ++p) {
    int o = o_l + 16 * p;
    float4 v = *reinterpret_cast<const float4*>(
        &W[((size_t)h * SSZ + og + o) * CDF + cg + c4]);
    Tt[c4 + 0][o] = v.x; Tt[c4 + 1][o] = v.y;
    Tt[c4 + 2][o] = v.z; Tt[c4 + 3][o] = v.w;
  }
  __syncthreads();
  int c_l = t >> 2;
#pragma unroll
  for (int p = 0; p < 4; ++p) {
    int oq = (t & 3) + 4 * p;
    int o0 = oq * 4;
    __hip_bfloat16 hv[4], lv[4];
#pragma unroll
    for (int j = 0; j < 4; ++j)
      split_bf16(Tt[c_l][o0 + j], hv[j], lv[j]);
    size_t base = ((size_t)h * CDF + cg + c_l) * SSZ + og + o0;
#pragma unroll
    for (int j = 0; j < 4; ++j) { wth[base + j] = hv[j]; wtl[base + j] = lv[j]; }
  }
}

// ---------------------------------------------------------------------------
// K1 (MFMA): M[bh][i][c] = sum_o wc[b][i][o] * W[h][o][c]
// ---------------------------------------------------------------------------
__global__ __launch_bounds__(256) void k1_mfma(const __hip_bfloat16* __restrict__ wch,
                                               const __hip_bfloat16* __restrict__ wcl,
                                               const __hip_bfloat16* __restrict__ wth,
                                               const __hip_bfloat16* __restrict__ wtl,
                                               float* __restrict__ Mout) {
  __shared__ __align__(16) short Ah[IDF * 32];
  __shared__ __align__(16) short Al[IDF * 32];
  __shared__ __align__(16) short Bh[CDF * 32];
  __shared__ __align__(16) short Bl[CDF * 32];

  int bh = blockIdx.x; int b = bh >> 3, h = bh & 7;
  int t = threadIdx.x;
  int lane = t & 63, wave = t >> 6;
  int ln15 = lane & 15, kh = lane >> 4;

  int rA = t >> 2, qA = t & 3;
  int qs = qA ^ ((rA >> 1) & 3);

  const short* gA_h = (const short*)wch + ((size_t)b * IDF + rA) * SSZ;
  const short* gA_l = (const short*)wcl + ((size_t)b * IDF + rA) * SSZ;
  const short* gB_h = (const short*)wth + ((size_t)h * CDF) * SSZ;
  const short* gB_l = (const short*)wtl + ((size_t)h * CDF) * SSZ;

  f32x4 acc[4][4] = {};

  int offA[4], offB[4];
#pragma unroll
  for (int r = 0; r < 4; ++r) {
    int row = r * 16 + ln15;
    offA[r] = row * 32 + ((kh ^ ((row >> 1) & 3)) * 8);
  }
#pragma unroll
  for (int c = 0; c < 4; ++c) {
    int row = wave * 64 + c * 16 + ln15;
    offB[c] = row * 32 + ((kh ^ ((row >> 1) & 3)) * 8);
  }

#pragma unroll 1
  for (int k0 = 0; k0 < SSZ; k0 += 32) {
    int4 va_h = *reinterpret_cast<const int4*>(&gA_h[k0 + qA * 8]);
    int4 va_l = *reinterpret_cast<const int4*>(&gA_l[k0 + qA * 8]);
    int4 vb_h[4], vb_l[4];
#pragma unroll
    for (int j = 0; j < 4; ++j) {
      size_t ga = (size_t)(j * 64 + rA) * SSZ + k0 + qA * 8;
      vb_h[j] = *reinterpret_cast<const int4*>(&gB_h[ga]);
      vb_l[j] = *reinterpret_cast<const int4*>(&gB_l[ga]);
    }
    __syncthreads();
    *reinterpret_cast<int4*>(&Ah[rA * 32 + qs * 8]) = va_h;
    *reinterpret_cast<int4*>(&Al[rA * 32 + qs * 8]) = va_l;
#pragma unroll
    for (int j = 0; j < 4; ++j) {
      *reinterpret_cast<int4*>(&Bh[(j * 64 + rA) * 32 + qs * 8]) = vb_h[j];
      *reinterpret_cast<int4*>(&Bl[(j * 64 + rA) * 32 + qs * 8]) = vb_l[j];
    }
    __syncthreads();
    short8v fa_h[4], fa_l[4], fb_h[4], fb_l[4];
#pragma unroll
    for (int r = 0; r < 4; ++r) {
      fa_h[r] = *reinterpret_cast<const short8v*>(&Ah[offA[r]]);
      fa_l[r] = *reinterpret_cast<const short8v*>(&Al[offA[r]]);
    }
#pragma unroll
    for (int c = 0; c < 4; ++c) {
      fb_h[c] = *reinterpret_cast<const short8v*>(&Bh[offB[c]]);
      fb_l[c] = *reinterpret_cast<const short8v*>(&Bl[offB[c]]);
    }
#pragma unroll
    for (int r = 0; r < 4; ++r)
#pragma unroll
      for (int c = 0; c < 4; ++c) {
        acc[r][c] = __builtin_amdgcn_mfma_f32_16x16x32_bf16(fa_h[r], fb_h[c], acc[r][c], 0, 0, 0);
        acc[r][c] = __builtin_amdgcn_mfma_f32_16x16x32_bf16(fa_h[r], fb_l[c], acc[r][c], 0, 0, 0);
        acc[r][c] = __builtin_amdgcn_mfma_f32_16x16x32_bf16(fa_l[r], fb_h[c], acc[r][c], 0, 0, 0);
      }
  }

  float* out = Mout + (size_t)bh * IDF * CDF;
  int rowq = (lane >> 4) * 4;
  int colb = wave * 64 + ln15;
#pragma unroll
  for (int r = 0; r < 4; ++r)
#pragma unroll
    for (int c = 0; c < 4; ++c)
#pragma unroll
      for (int reg = 0; reg < 4; ++reg)
        out[(r * 16 + rowq + reg) * CDF + colb + c * 16] = acc[r][c][reg];
}

// ---------------------------------------------------------------------------
// K2: logits[bh][i][l] = sum_c M[bh][i][c] * ctx[b][c][l]; softmax over l
// ---------------------------------------------------------------------------
__global__ __launch_bounds__(256) void k_attn(const float* __restrict__ Mm,
                                              const float* __restrict__ ctx,
                                              float* __restrict__ attn) {
  __shared__ float As[IDF][32];
  __shared__ float Bs[32][LL];
  int bh = blockIdx.x; int b = bh >> 3;
  const float* A  = Mm + (size_t)bh * IDF * CDF;
  const float* Bm = ctx + (size_t)b * CDF * LL;
  int tid = threadIdx.x;
  int tc = tid & 31, ti = tid >> 5;
  int c0 = tc * 8, i0 = ti * 8;
  float acc[8][8];
#pragma unroll
  for (int r = 0; r < 8; ++r)
#pragma unroll
    for (int s = 0; s < 8; ++s) acc[r][s] = 0.f;

  for (int k0 = 0; k0 < CDF; k0 += 32) {
#pragma unroll
    for (int p = 0; p < 2; ++p) {
      int f = tid + p * 256;
      int row = f >> 3, seg = f & 7;
      *reinterpret_cast<float4*>(&As[row][seg * 4]) =
          *reinterpret_cast<const float4*>(&A[row * CDF + k0 + seg * 4]);
    }
#pragma unroll
    for (int p = 0; p < 8; ++p) {
      int f = tid + p * 256;
      int kk = f >> 6, cs = f & 63;
      *reinterpret_cast<float4*>(&Bs[kk][cs * 4]) =
          *reinterpret_cast<const float4*>(&Bm[(size_t)(k0 + kk) * LL + cs * 4]);
    }
    __syncthreads();
#pragma unroll
    for (int kq = 0; kq < 8; ++kq) {
      float4 av[8];
#pragma unroll
      for (int r = 0; r < 8; ++r)
        av[r] = *reinterpret_cast<const float4*>(&As[i0 + r][kq * 4]);
#pragma unroll
      for (int kk = 0; kk < 4; ++kk) {
        float4 b0 = *reinterpret_cast<const float4*>(&Bs[kq * 4 + kk][c0]);
        float4 b1 = *reinterpret_cast<const float4*>(&Bs[kq * 4 + kk][c0 + 4]);
        float bv[8] = {b0.x, b0.y, b0.z, b0.w, b1.x, b1.y, b1.z, b1.w};
#pragma unroll
        for (int r = 0; r < 8; ++r) {
          float a = (kk == 0) ? av[r].x : (kk == 1) ? av[r].y : (kk == 2) ? av[r].z : av[r].w;
#pragma unroll
          for (int s = 0; s < 8; ++s) acc[r][s] += a * bv[s];
        }
      }
    }
    __syncthreads();
  }
  float* out = attn + (size_t)bh * IDF * LL;
#pragma unroll
  for (int r = 0; r < 8; ++r) {
    float mx = acc[r][0];
#pragma unroll
    for (int s = 1; s < 8; ++s) mx = fmaxf(mx, acc[r][s]);
#pragma unroll
    for (int m = 16; m >= 1; m >>= 1) mx = fmaxf(mx, __shfl_xor(mx, m, 64));
    float ex[8]; float sum = 0.f;
#pragma unroll
    for (int s = 0; s < 8; ++s) { ex[s] = __expf(acc[r][s] - mx); sum += ex[s]; }
#pragma unroll
    for (int m = 16; m >= 1; m >>= 1) sum += __shfl_xor(sum, m, 64);
    float inv = 1.f / sum;
    float4 v0 = {ex[0] * inv, ex[1] * inv, ex[2] * inv, ex[3] * inv};
    float4 v1 = {ex[4] * inv, ex[5] * inv, ex[6] * inv, ex[7] * inv};
    *reinterpret_cast<float4*>(&out[(i0 + r) * LL + c0]) = v0;
    *reinterpret_cast<float4*>(&out[(i0 + r) * LL + c0 + 4]) = v1;
  }
}

// ---------------------------------------------------------------------------
// K3: N2{h,l}[b][i][h*256+c] = split(sum_l attn[bh][i][l]*ctx[b][c][l])
// ---------------------------------------------------------------------------
__global__ __launch_bounds__(256) void k_N2(const float* __restrict__ attn,
                                            const float* __restrict__ ctx,
                                            __hip_bfloat16* __restrict__ N2h,
                                            __hip_bfloat16* __restrict__ N2l) {
  __shared__ float As[IDF][32];    // [i][l]
  __shared__ float Bs[32][260];    // [l][c], padded
  int bh = blockIdx.x; int b = bh >> 3, h = bh & 7;
  const float* A  = attn + (size_t)bh * IDF * LL;
  const float* Cm = ctx + (size_t)b * CDF * LL;
  int tid = threadIdx.x;
  int tc = tid & 31, ti = tid >> 5;
  int c0 = tc * 8, i0 = ti * 8;
  float acc[8][8];
#pragma unroll
  for (int r = 0; r < 8; ++r)
#pragma unroll
    for (int s = 0; s < 8; ++s) acc[r][s] = 0.f;

  for (int l0 = 0; l0 < LL; l0 += 32) {
#pragma unroll
    for (int p = 0; p < 2; ++p) {
      int f = tid + p * 256;
      int row = f >> 3, seg = f & 7;
      *reinterpret_cast<float4*>(&As[row][seg * 4]) =
          *reinterpret_cast<const float4*>(&A[row * LL + l0 + seg * 4]);
    }
#pragma unroll
    for (int p = 0; p < 8; ++p) {
      int f = tid + p * 256;
      int c = f >> 3, seg = f & 7;
      float4 v = *reinterpret_cast<const float4*>(&Cm[c * LL + l0 + seg * 4]);
      Bs[seg * 4 + 0][c] = v.x; Bs[seg * 4 + 1][c] = v.y;
      Bs[seg * 4 + 2][c] = v.z; Bs[seg * 4 + 3][c] = v.w;
    }
    __syncthreads();
#pragma unroll
    for (int kq = 0; kq < 8; ++kq) {
      float4 av[8];
#pragma unroll
      for (int r = 0; r < 8; ++r)
        av[r] = *reinterpret_cast<const float4*>(&As[i0 + r][kq * 4]);
#pragma unroll
      for (int kk = 0; kk < 4; ++kk) {
        float4 b0 = *reinterpret_cast<const float4*>(&Bs[kq * 4 + kk][c0]);
        float4 b1 = *reinterpret_cast<const float4*>(&Bs[kq * 4 + kk][c0 + 4]);
        float bv[8] = {b0.x, b0.y, b0.z, b0.w, b1.x, b1.y, b1.z, b1.w};
#pragma unroll
        for (int r = 0; r < 8; ++r) {
          float a = (kk == 0) ? av[r].x : (kk == 1) ? av[r].y : (kk == 2) ? av[r].z : av[r].w;
#pragma unroll
          for (int s = 0; s < 8; ++s) acc[r][s] += a * bv[s];
        }
      }
    }
    __syncthreads();
  }
  // epilogue: split to bf16 hi/lo, write [b][i][h*256+c]
  size_t base = (size_t)b * IDF * KHC + h * CDF;
#pragma unroll
  for (int r = 0; r < 8; ++r) {
    __align__(16) __hip_bfloat16 hb[8], lb[8];
#pragma unroll
    for (int s = 0; s < 8; ++s) split_bf16(acc[r][s], hb[s], lb[s]);
    size_t idx = base + (size_t)(i0 + r) * KHC + c0;
    *reinterpret_cast<int4*>(&N2h[idx]) = *reinterpret_cast<int4*>(hb);
    *reinterpret_cast<int4*>(&N2l[idx]) = *reinterpret_cast<int4*>(lb);
  }
}

// ---------------------------------------------------------------------------
// K4 (MFMA): ctx_out[b][i][o] = sum_{h,c} N2[b][i][hc] * W[h][o][c]
// NT split-bf16: A = N2 [i][k=hc], B = W [o][c] (k=c contig within h).
// grid = g(2) x b(32) x ot(8 of 128 o). 4 waves x (64i x 32o). kstep=32.
// ---------------------------------------------------------------------------
__global__ __launch_bounds__(256) void k4_mfma(const __hip_bfloat16* __restrict__ N2h,
                                               const __hip_bfloat16* __restrict__ N2l,
                                               const __hip_bfloat16* __restrict__ Wh,
                                               const __hip_bfloat16* __restrict__ Wl,
                                               float* __restrict__ out0,
                                               float* __restrict__ out1) {
  __shared__ __align__(16) short Ah[IDF * 32];
  __shared__ __align__(16) short Al[IDF * 32];
  __shared__ __align__(16) short Bh[128 * 32];
  __shared__ __align__(16) short Bl[128 * 32];

  int blk = blockIdx.x;
  int g = blk >> 8;
  int r8 = blk & 255;
  int b = r8 >> 3, ot = r8 & 7;
  int obase = ot * 128;
  int t = threadIdx.x;
  int lane = t & 63, wave = t >> 6;
  int ln15 = lane & 15, kh = lane >> 4;

  int rA = t >> 2, qA = t & 3;
  int qs = qA ^ ((rA >> 1) & 3);

  const short* gA_h = (const short*)N2h + ((size_t)b * IDF + rA) * KHC;
  const short* gA_l = (const short*)N2l + ((size_t)b * IDF + rA) * KHC;
  const short* gB_h = (const short*)Wh;
  const short* gB_l = (const short*)Wl;

  f32x4 acc[4][2] = {};

  int offA[4], offB[2];
#pragma unroll
  for (int r = 0; r < 4; ++r) {
    int row = r * 16 + ln15;
    offA[r] = row * 32 + ((kh ^ ((row >> 1) & 3)) * 8);
  }
#pragma unroll
  for (int c = 0; c < 2; ++c) {
    int row = wave * 32 + c * 16 + ln15;
    offB[c] = row * 32 + ((kh ^ ((row >> 1) & 3)) * 8);
  }

  int kbase = g * (KHC / 2);
#pragma unroll 1
  for (int k0 = 0; k0 < KHC / 2; k0 += 32) {
    int kk0 = kbase + k0;
    int h = kk0 >> 8, cbase = kk0 & 255;
    int4 va_h = *reinterpret_cast<const int4*>(&gA_h[kk0 + qA * 8]);
    int4 va_l = *reinterpret_cast<const int4*>(&gA_l[kk0 + qA * 8]);
    int4 vb_h[2], vb_l[2];
#pragma unroll
    for (int j = 0; j < 2; ++j) {
      size_t ga = ((size_t)h * SSZ + obase + j * 64 + rA) * CDF + cbase + qA * 8;
      vb_h[j] = *reinterpret_cast<const int4*>(&gB_h[ga]);
      vb_l[j] = *reinterpret_cast<const int4*>(&gB_l[ga]);
    }
    __syncthreads();
    *reinterpret_cast<int4*>(&Ah[rA * 32 + qs * 8]) = va_h;
    *reinterpret_cast<int4*>(&Al[rA * 32 + qs * 8]) = va_l;
#pragma unroll
    for (int j = 0; j < 2; ++j) {
      *reinterpret_cast<int4*>(&Bh[(j * 64 + rA) * 32 + qs * 8]) = vb_h[j];
      *reinterpret_cast<int4*>(&Bl[(j * 64 + rA) * 32 + qs * 8]) = vb_l[j];
    }
    __syncthreads();
    short8v fa_h[4], fa_l[4], fb_h[2], fb_l[2];
#pragma unroll
    for (int r = 0; r < 4; ++r) {
      fa_h[r] = *reinterpret_cast<const short8v*>(&Ah[offA[r]]);
      fa_l[r] = *reinterpret_cast<const short8v*>(&Al[offA[r]]);
    }
#pragma unroll
    for (int c = 0; c < 2; ++c) {
      fb_h[c] = *reinterpret_cast<const short8v*>(&Bh[offB[c]]);
      fb_l[c] = *reinterpret_cast<const short8v*>(&Bl[offB[c]]);
    }
#pragma unroll
    for (int r = 0; r < 4; ++r)
#pragma unroll
      for (int c = 0; c < 2; ++c) {
        acc[r][c] = __builtin_amdgcn_mfma_f32_16x16x32_bf16(fa_h[r], fb_h[c], acc[r][c], 0, 0, 0);
        acc[r][c] = __builtin_amdgcn_mfma_f32_16x16x32_bf16(fa_h[r], fb_l[c], acc[r][c], 0, 0, 0);
        acc[r][c] = __builtin_amdgcn_mfma_f32_16x16x32_bf16(fa_l[r], fb_h[c], acc[r][c], 0, 0, 0);
      }
  }

  float* dst = (g == 0) ? out0 : out1;
  int rowq = (lane >> 4) * 4;
#pragma unroll
  for (int r = 0; r < 4; ++r)
#pragma unroll
    for (int c = 0; c < 2; ++c)
#pragma unroll
      for (int reg = 0; reg < 4; ++reg)
        dst[((size_t)b * IDF + r * 16 + rowq + reg) * SSZ +
            obase + wave * 32 + c * 16 + ln15] = acc[r][c][reg];
}

// out += P
__global__ __launch_bounds__(256) void k_add(float* __restrict__ out,
                                             const float* __restrict__ P) {
  int idx = blockIdx.x * 256 + threadIdx.x;
  float4 a = reinterpret_cast<float4*>(out)[idx];
  float4 p = reinterpret_cast<const float4*>(P)[idx];
  a.x += p.x; a.y += p.y; a.z += p.z; a.w += p.w;
  reinterpret_cast<float4*>(out)[idx] = a;
}

// ---------------------------------------------------------------------------
// K5: attn_out[b][l][i] = sum_h attn[bh][i][l]
// ---------------------------------------------------------------------------
__global__ __launch_bounds__(256) void k_attnout(const float* __restrict__ attn,
                                                 float* __restrict__ outa) {
  __shared__ float T[64][65];
  int blk = blockIdx.x; int b = blk >> 2, lt = blk & 3;
  int l0 = lt * 64;
  int tid = threadIdx.x;
  float4 acc[4];
#pragma unroll
  for (int p = 0; p < 4; ++p) acc[p] = make_float4(0.f, 0.f, 0.f, 0.f);
  for (int h = 0; h < NH; ++h) {
    const float* src = attn + (size_t)(b * NH + h) * IDF * LL;
#pragma unroll
    for (int p = 0; p < 4; ++p) {
      int f = tid + p * 256;
      int i = f >> 4, lc = (f & 15) * 4;
      float4 v = *reinterpret_cast<const float4*>(&src[i * LL + l0 + lc]);
      acc[p].x += v.x; acc[p].y += v.y; acc[p].z += v.z; acc[p].w += v.w;
    }
  }
#pragma unroll
  for (int p = 0; p < 4; ++p) {
    int f = tid + p * 256;
    int i = f >> 4, lc = (f & 15) * 4;
    T[i][lc + 0] = acc[p].x; T[i][lc + 1] = acc[p].y;
    T[i][lc + 2] = acc[p].z; T[i][lc + 3] = acc[p].w;
  }
  __syncthreads();
#pragma unroll
  for (int p = 0; p < 4; ++p) {
    int f = tid + p * 256;
    int lr = f >> 4, ic = (f & 15) * 4;
    float4 v = {T[ic + 0][lr], T[ic + 1][lr], T[ic + 2][lr], T[ic + 3][lr]};
    *reinterpret_cast<float4*>(&outa[((size_t)b * LL + l0 + lr) * IDF + ic]) = v;
  }
}

// ---------------------------------------------------------------------------
extern "C" void kernel_launch(void* const* d_in, const int* in_sizes, int n_in,
                              void* d_out, int out_size, void* d_ws, size_t ws_size,
                              hipStream_t stream) {
  const float* wc  = (const float*)d_in[0];   // [32][64][1024]
  const float* ctx = (const float*)d_in[1];   // [32][256][256]
  const float* W   = (const float*)d_in[2];   // [8][1024][256]
  float* out = (float*)d_out;

  // Region A (4.19M floats): M (fp32) -> N2h/N2l (bf16)
  float* RA = (float*)d_ws;
  // Region B (4.19M floats): wc/Wt splits -> attn -> {Pbuf, Wh/Wl}
  float* RB = RA + (size_t)4194304;

  float* Mbuf = RA;
  __hip_bfloat16* N2h = (__hip_bfloat16*)RA;                 // 4.19M bf16
  __hip_bfloat16* N2l = N2h + (size_t)BB * IDF * KHC;        // 4.19M bf16

  __hip_bfloat16* wch = (__hip_bfloat16*)RB;                 // 2.1M bf16
  __hip_bfloat16* wcl = wch + (size_t)BB * IDF * SSZ;
  __hip_bfloat16* wth = wcl + (size_t)BB * IDF * SSZ;
  __hip_bfloat16* wtl = wth + (size_t)NH * CDF * SSZ;
  float* Abuf = RB;                                          // attn, 4.19M floats
  float* Pbuf = RB;                                          // 2.1M floats
  __hip_bfloat16* Wh = (__hip_bfloat16*)(RB + (size_t)2097152);
  __hip_bfloat16* Wl = Wh + (size_t)NH * SSZ * CDF;

  k_split_wc<<<2048, 256, 0, stream>>>(wc, wch, wcl);
  k_split_Wt<<<512, 256, 0, stream>>>(W, wth, wtl);
  k1_mfma   <<<BB * NH, 256, 0, stream>>>(wch, wcl, wth, wtl, Mbuf);
  k_attn    <<<BB * NH, 256, 0, stream>>>(Mbuf, ctx, Abuf);
  k_N2      <<<BB * NH, 256, 0, stream>>>(Abuf, ctx, N2h, N2l);
  k_attnout <<<BB * 4, 256, 0, stream>>>(Abuf, out + (size_t)BB * IDF * SSZ);
  k_split_W <<<2048, 256, 0, stream>>>(W, Wh, Wl);
  k4_mfma   <<<512, 256, 0, stream>>>(N2h, N2l, Wh, Wl, out, Pbuf);
  k_add     <<<2048, 256, 0, stream>>>(out, Pbuf);
}

// Round 5
// 268.534 us; speedup vs baseline: 1.9058x; 1.1069x over previous
//
#include <hip/hip_runtime.h>
#include <hip/hip_bf16.h>

#define BB 32
#define IDF 64
#define CDF 256
#define SSZ 1024
#define NH 8
#define LL 256
#define KHC 2048   // NH*CDF

typedef __attribute__((ext_vector_type(8))) short short8v;   // 8 bf16 (4 VGPR)
typedef __attribute__((ext_vector_type(4))) float f32x4;     // MFMA acc

__device__ inline void split_bf16(float x, __hip_bfloat16& h, __hip_bfloat16& l) {
  h = __float2bfloat16(x);
  l = __float2bfloat16(x - __bfloat162float(h));
}

// ---------------------------------------------------------------------------
// Split wc (fp32) -> wch, wcl (bf16 hi/lo), same [b][i][o] layout.
// ---------------------------------------------------------------------------
__global__ __launch_bounds__(256) void k_split_wc(const float* __restrict__ wc,
                                                  __hip_bfloat16* __restrict__ wch,
                                                  __hip_bfloat16* __restrict__ wcl) {
  int idx = (blockIdx.x * 256 + threadIdx.x) * 4;
  float4 v = *reinterpret_cast<const float4*>(&wc[idx]);
  __align__(16) __hip_bfloat16 hb[4], lb[4];
  split_bf16(v.x, hb[0], lb[0]); split_bf16(v.y, hb[1], lb[1]);
  split_bf16(v.z, hb[2], lb[2]); split_bf16(v.w, hb[3], lb[3]);
  *reinterpret_cast<int2*>(&wch[idx]) = *reinterpret_cast<int2*>(hb);
  *reinterpret_cast<int2*>(&wcl[idx]) = *reinterpret_cast<int2*>(lb);
}

// ---------------------------------------------------------------------------
// Split W (fp32, [h][o][c]) -> Wh, Wl (bf16, same layout). For K4.
// ---------------------------------------------------------------------------
__global__ __launch_bounds__(256) void k_split_W(const float* __restrict__ W,
                                                 __hip_bfloat16* __restrict__ Wh,
                                                 __hip_bfloat16* __restrict__ Wl) {
  int idx = (blockIdx.x * 256 + threadIdx.x) * 4;
  float4 v = *reinterpret_cast<const float4*>(&W[idx]);
  __align__(16) __hip_bfloat16 hb[4], lb[4];
  split_bf16(v.x, hb[0], lb[0]); split_bf16(v.y, hb[1], lb[1]);
  split_bf16(v.z, hb[2], lb[2]); split_bf16(v.w, hb[3], lb[3]);
  *reinterpret_cast<int2*>(&Wh[idx]) = *reinterpret_cast<int2*>(hb);
  *reinterpret_cast<int2*>(&Wl[idx]) = *reinterpret_cast<int2*>(lb);
}

// ---------------------------------------------------------------------------
// Split+transpose W[h][o][c] (fp32) -> Wt hi/lo [h][c][o] (bf16). For K1.
// ---------------------------------------------------------------------------
__global__ __launch_bounds__(256) void k_split_Wt(const float* __restrict__ W,
                                                  __hip_bfloat16* __restrict__ wth,
                                                  __hip_bfloat16* __restrict__ wtl) {
  __shared__ float Tt[64][65];   // [c][o]
  int blk = blockIdx.x;
  int h = blk >> 6, ot = (blk >> 2) & 15, ct = blk & 3;
  int og = ot * 64, cg = ct * 64;
  int t = threadIdx.x;
  int o_l = t >> 4, c4 = (t & 15) * 4;
#pragma unroll
  for (int p = 0; p < 4; ++p) {
    int o = o_l + 16 * p;
    float4 v = *reinterpret_cast<const float4*>(
        &W[((size_t)h * SSZ + og + o) * CDF + cg + c4]);
    Tt[c4 + 0][o] = v.x; Tt[c4 + 1][o] = v.y;
    Tt[c4 + 2][o] = v.z; Tt[c4 + 3][o] = v.w;
  }
  __syncthreads();
  int c_l = t >> 2;
#pragma unroll
  for (int p = 0; p < 4; ++p) {
    int oq = (t & 3) + 4 * p;
    int o0 = oq * 4;
    __hip_bfloat16 hv[4], lv[4];
#pragma unroll
    for (int j = 0; j < 4; ++j)
      split_bf16(Tt[c_l][o0 + j], hv[j], lv[j]);
    size_t base = ((size_t)h * CDF + cg + c_l) * SSZ + og + o0;
#pragma unroll
    for (int j = 0; j < 4; ++j) { wth[base + j] = hv[j]; wtl[base + j] = lv[j]; }
  }
}

// ---------------------------------------------------------------------------
// K1 (MFMA, pipelined): M[bh][i][c] = sum_o wc[b][i][o] * W[h][o][c]
// grid 512: (bh, nh-half). Per block 64i x 128c. 4 waves x (64i x 32c).
// Double-buffered LDS, register prefetch, ONE barrier per k-step.
// ---------------------------------------------------------------------------
__global__ __launch_bounds__(256) void k1_mfma(const __hip_bfloat16* __restrict__ wch,
                                               const __hip_bfloat16* __restrict__ wcl,
                                               const __hip_bfloat16* __restrict__ wth,
                                               const __hip_bfloat16* __restrict__ wtl,
                                               float* __restrict__ Mout) {
  __shared__ __align__(16) short Ah[2][IDF * 32];
  __shared__ __align__(16) short Al[2][IDF * 32];
  __shared__ __align__(16) short Bh[2][128 * 32];
  __shared__ __align__(16) short Bl[2][128 * 32];

  int blk = blockIdx.x;
  int bh = blk >> 1, nh = blk & 1;
  int b = bh >> 3, h = bh & 7;
  int t = threadIdx.x;
  int lane = t & 63, wave = t >> 6;
  int ln15 = lane & 15, kh = lane >> 4;

  int rA = t >> 2, qA = t & 3;
  int qs = qA ^ ((rA >> 1) & 3);

  const short* gA_h = (const short*)wch + ((size_t)b * IDF + rA) * SSZ;
  const short* gA_l = (const short*)wcl + ((size_t)b * IDF + rA) * SSZ;
  const short* gB_h = (const short*)wth + ((size_t)(h * CDF + nh * 128)) * SSZ;
  const short* gB_l = (const short*)wtl + ((size_t)(h * CDF + nh * 128)) * SSZ;

  f32x4 acc[4][2] = {};

  int offA[4], offB[2];
#pragma unroll
  for (int r = 0; r < 4; ++r) {
    int row = r * 16 + ln15;
    offA[r] = row * 32 + ((kh ^ ((row >> 1) & 3)) * 8);
  }
#pragma unroll
  for (int c = 0; c < 2; ++c) {
    int row = wave * 32 + c * 16 + ln15;
    offB[c] = row * 32 + ((kh ^ ((row >> 1) & 3)) * 8);
  }

  int4 va_h, va_l, vb_h[2], vb_l[2];
  // prologue: G2R(k=0), R2LDS(buf 0)
  va_h = *reinterpret_cast<const int4*>(&gA_h[qA * 8]);
  va_l = *reinterpret_cast<const int4*>(&gA_l[qA * 8]);
#pragma unroll
  for (int j = 0; j < 2; ++j) {
    size_t ga = (size_t)(j * 64 + rA) * SSZ + qA * 8;
    vb_h[j] = *reinterpret_cast<const int4*>(&gB_h[ga]);
    vb_l[j] = *reinterpret_cast<const int4*>(&gB_l[ga]);
  }
  *reinterpret_cast<int4*>(&Ah[0][rA * 32 + qs * 8]) = va_h;
  *reinterpret_cast<int4*>(&Al[0][rA * 32 + qs * 8]) = va_l;
#pragma unroll
  for (int j = 0; j < 2; ++j) {
    *reinterpret_cast<int4*>(&Bh[0][(j * 64 + rA) * 32 + qs * 8]) = vb_h[j];
    *reinterpret_cast<int4*>(&Bl[0][(j * 64 + rA) * 32 + qs * 8]) = vb_l[j];
  }

#pragma unroll 1
  for (int ks = 0; ks < 32; ++ks) {
    int cur = ks & 1;
    __syncthreads();               // buf[cur] writes visible; prev reads drained
    if (ks < 31) {                 // issue next k-step's global loads EARLY
      int k0 = (ks + 1) * 32;
      va_h = *reinterpret_cast<const int4*>(&gA_h[k0 + qA * 8]);
      va_l = *reinterpret_cast<const int4*>(&gA_l[k0 + qA * 8]);
#pragma unroll
      for (int j = 0; j < 2; ++j) {
        size_t ga = (size_t)(j * 64 + rA) * SSZ + k0 + qA * 8;
        vb_h[j] = *reinterpret_cast<const int4*>(&gB_h[ga]);
        vb_l[j] = *reinterpret_cast<const int4*>(&gB_l[ga]);
      }
    }
    short8v fa_h[4], fa_l[4], fb_h[2], fb_l[2];
#pragma unroll
    for (int r = 0; r < 4; ++r) {
      fa_h[r] = *reinterpret_cast<const short8v*>(&Ah[cur][offA[r]]);
      fa_l[r] = *reinterpret_cast<const short8v*>(&Al[cur][offA[r]]);
    }
#pragma unroll
    for (int c = 0; c < 2; ++c) {
      fb_h[c] = *reinterpret_cast<const short8v*>(&Bh[cur][offB[c]]);
      fb_l[c] = *reinterpret_cast<const short8v*>(&Bl[cur][offB[c]]);
    }
#pragma unroll
    for (int r = 0; r < 4; ++r)
#pragma unroll
      for (int c = 0; c < 2; ++c) {
        acc[r][c] = __builtin_amdgcn_mfma_f32_16x16x32_bf16(fa_h[r], fb_h[c], acc[r][c], 0, 0, 0);
        acc[r][c] = __builtin_amdgcn_mfma_f32_16x16x32_bf16(fa_h[r], fb_l[c], acc[r][c], 0, 0, 0);
        acc[r][c] = __builtin_amdgcn_mfma_f32_16x16x32_bf16(fa_l[r], fb_h[c], acc[r][c], 0, 0, 0);
      }
    if (ks < 31) {                 // write prefetched data to the other buffer
      int nxt = cur ^ 1;
      *reinterpret_cast<int4*>(&Ah[nxt][rA * 32 + qs * 8]) = va_h;
      *reinterpret_cast<int4*>(&Al[nxt][rA * 32 + qs * 8]) = va_l;
#pragma unroll
      for (int j = 0; j < 2; ++j) {
        *reinterpret_cast<int4*>(&Bh[nxt][(j * 64 + rA) * 32 + qs * 8]) = vb_h[j];
        *reinterpret_cast<int4*>(&Bl[nxt][(j * 64 + rA) * 32 + qs * 8]) = vb_l[j];
      }
    }
  }

  float* out = Mout + (size_t)bh * IDF * CDF + nh * 128;
  int rowq = (lane >> 4) * 4;
#pragma unroll
  for (int r = 0; r < 4; ++r)
#pragma unroll
    for (int c = 0; c < 2; ++c)
#pragma unroll
      for (int reg = 0; reg < 4; ++reg)
        out[(r * 16 + rowq + reg) * CDF + wave * 32 + c * 16 + ln15] = acc[r][c][reg];
}

// ---------------------------------------------------------------------------
// K2: logits[bh][i][l] = sum_c M[bh][i][c] * ctx[b][c][l]; softmax over l.
// grid 512: (bh, i-half of 32). acc[4][8].
// ---------------------------------------------------------------------------
__global__ __launch_bounds__(256) void k_attn(const float* __restrict__ Mm,
                                              const float* __restrict__ ctx,
                                              float* __restrict__ attn) {
  __shared__ float As[32][32];
  __shared__ float Bs[32][LL];
  int blk = blockIdx.x;
  int bh = blk >> 1, ih = blk & 1;
  int b = bh >> 3;
  int ibase = ih * 32;
  const float* A  = Mm + ((size_t)bh * IDF + ibase) * CDF;
  const float* Bm = ctx + (size_t)b * CDF * LL;
  int tid = threadIdx.x;
  int tc = tid & 31, ti = tid >> 5;
  int c0 = tc * 8, i0 = ti * 4;
  float acc[4][8];
#pragma unroll
  for (int r = 0; r < 4; ++r)
#pragma unroll
    for (int s = 0; s < 8; ++s) acc[r][s] = 0.f;

  for (int k0 = 0; k0 < CDF; k0 += 32) {
    {                                        // A tile: 32 rows x 8 f4
      int row = tid >> 3, seg = tid & 7;
      *reinterpret_cast<float4*>(&As[row][seg * 4]) =
          *reinterpret_cast<const float4*>(&A[row * CDF + k0 + seg * 4]);
    }
#pragma unroll
    for (int p = 0; p < 8; ++p) {            // B tile: 32 rows x 64 f4
      int f = tid + p * 256;
      int kk = f >> 6, cs = f & 63;
      *reinterpret_cast<float4*>(&Bs[kk][cs * 4]) =
          *reinterpret_cast<const float4*>(&Bm[(size_t)(k0 + kk) * LL + cs * 4]);
    }
    __syncthreads();
#pragma unroll
    for (int kq = 0; kq < 8; ++kq) {
      float4 av[4];
#pragma unroll
      for (int r = 0; r < 4; ++r)
        av[r] = *reinterpret_cast<const float4*>(&As[i0 + r][kq * 4]);
#pragma unroll
      for (int kk = 0; kk < 4; ++kk) {
        float4 b0 = *reinterpret_cast<const float4*>(&Bs[kq * 4 + kk][c0]);
        float4 b1 = *reinterpret_cast<const float4*>(&Bs[kq * 4 + kk][c0 + 4]);
        float bv[8] = {b0.x, b0.y, b0.z, b0.w, b1.x, b1.y, b1.z, b1.w};
#pragma unroll
        for (int r = 0; r < 4; ++r) {
          float a = (kk == 0) ? av[r].x : (kk == 1) ? av[r].y : (kk == 2) ? av[r].z : av[r].w;
#pragma unroll
          for (int s = 0; s < 8; ++s) acc[r][s] += a * bv[s];
        }
      }
    }
    __syncthreads();
  }
  float* out = attn + ((size_t)bh * IDF + ibase) * LL;
#pragma unroll
  for (int r = 0; r < 4; ++r) {
    float mx = acc[r][0];
#pragma unroll
    for (int s = 1; s < 8; ++s) mx = fmaxf(mx, acc[r][s]);
#pragma unroll
    for (int m = 16; m >= 1; m >>= 1) mx = fmaxf(mx, __shfl_xor(mx, m, 64));
    float ex[8]; float sum = 0.f;
#pragma unroll
    for (int s = 0; s < 8; ++s) { ex[s] = __expf(acc[r][s] - mx); sum += ex[s]; }
#pragma unroll
    for (int m = 16; m >= 1; m >>= 1) sum += __shfl_xor(sum, m, 64);
    float inv = 1.f / sum;
    float4 v0 = {ex[0] * inv, ex[1] * inv, ex[2] * inv, ex[3] * inv};
    float4 v1 = {ex[4] * inv, ex[5] * inv, ex[6] * inv, ex[7] * inv};
    *reinterpret_cast<float4*>(&out[(i0 + r) * LL + c0]) = v0;
    *reinterpret_cast<float4*>(&out[(i0 + r) * LL + c0 + 4]) = v1;
  }
}

// ---------------------------------------------------------------------------
// K3: N2{h,l}[b][i][h*256+c] = split(sum_l attn[bh][i][l]*ctx[b][c][l])
// grid 512: (bh, c-half of 128). acc[4][8].
// ---------------------------------------------------------------------------
__global__ __launch_bounds__(256) void k_N2(const float* __restrict__ attn,
                                            const float* __restrict__ ctx,
                                            __hip_bfloat16* __restrict__ N2h,
                                            __hip_bfloat16* __restrict__ N2l) {
  __shared__ float As[IDF][32];    // [i][l]
  __shared__ float Bs[32][132];    // [l][c], padded
  int blk = blockIdx.x;
  int bh = blk >> 1, ch = blk & 1;
  int b = bh >> 3, h = bh & 7;
  int cgbase = ch * 128;
  const float* A  = attn + (size_t)bh * IDF * LL;
  const float* Cm = ctx + ((size_t)b * CDF + cgbase) * LL;
  int tid = threadIdx.x;
  int tc = tid & 15, ti = tid >> 4;
  int c0 = tc * 8, i0 = ti * 4;
  float acc[4][8];
#pragma unroll
  for (int r = 0; r < 4; ++r)
#pragma unroll
    for (int s = 0; s < 8; ++s) acc[r][s] = 0.f;

  for (int l0 = 0; l0 < LL; l0 += 32) {
#pragma unroll
    for (int p = 0; p < 2; ++p) {            // attn tile: 64 rows x 8 f4
      int f = tid + p * 256;
      int row = f >> 3, seg = f & 7;
      *reinterpret_cast<float4*>(&As[row][seg * 4]) =
          *reinterpret_cast<const float4*>(&A[row * LL + l0 + seg * 4]);
    }
#pragma unroll
    for (int p = 0; p < 4; ++p) {            // ctx tile: transpose-stage 128 rows
      int f = tid + p * 256;
      int c = f >> 3, seg = f & 7;
      float4 v = *reinterpret_cast<const float4*>(&Cm[(size_t)c * LL + l0 + seg * 4]);
      Bs[seg * 4 + 0][c] = v.x; Bs[seg * 4 + 1][c] = v.y;
      Bs[seg * 4 + 2][c] = v.z; Bs[seg * 4 + 3][c] = v.w;
    }
    __syncthreads();
#pragma unroll
    for (int kq = 0; kq < 8; ++kq) {
      float4 av[4];
#pragma unroll
      for (int r = 0; r < 4; ++r)
        av[r] = *reinterpret_cast<const float4*>(&As[i0 + r][kq * 4]);
#pragma unroll
      for (int kk = 0; kk < 4; ++kk) {
        float4 b0 = *reinterpret_cast<const float4*>(&Bs[kq * 4 + kk][c0]);
        float4 b1 = *reinterpret_cast<const float4*>(&Bs[kq * 4 + kk][c0 + 4]);
        float bv[8] = {b0.x, b0.y, b0.z, b0.w, b1.x, b1.y, b1.z, b1.w};
#pragma unroll
        for (int r = 0; r < 4; ++r) {
          float a = (kk == 0) ? av[r].x : (kk == 1) ? av[r].y : (kk == 2) ? av[r].z : av[r].w;
#pragma unroll
          for (int s = 0; s < 8; ++s) acc[r][s] += a * bv[s];
        }
      }
    }
    __syncthreads();
  }
  // epilogue: split to bf16 hi/lo, write [b][i][h*256 + cgbase + c]
  size_t base = (size_t)b * IDF * KHC + h * CDF + cgbase;
#pragma unroll
  for (int r = 0; r < 4; ++r) {
    __align__(16) __hip_bfloat16 hb[8], lb[8];
#pragma unroll
    for (int s = 0; s < 8; ++s) split_bf16(acc[r][s], hb[s], lb[s]);
    size_t idx = base + (size_t)(i0 + r) * KHC + c0;
    *reinterpret_cast<int4*>(&N2h[idx]) = *reinterpret_cast<int4*>(hb);
    *reinterpret_cast<int4*>(&N2l[idx]) = *reinterpret_cast<int4*>(lb);
  }
}

// ---------------------------------------------------------------------------
// K4 (MFMA): ctx_out[b][i][o] = sum_{h,c} N2[b][i][hc] * W[h][o][c]
// ---------------------------------------------------------------------------
__global__ __launch_bounds__(256) void k4_mfma(const __hip_bfloat16* __restrict__ N2h,
                                               const __hip_bfloat16* __restrict__ N2l,
                                               const __hip_bfloat16* __restrict__ Wh,
                                               const __hip_bfloat16* __restrict__ Wl,
                                               float* __restrict__ out0,
                                               float* __restrict__ out1) {
  __shared__ __align__(16) short Ah[IDF * 32];
  __shared__ __align__(16) short Al[IDF * 32];
  __shared__ __align__(16) short Bh[128 * 32];
  __shared__ __align__(16) short Bl[128 * 32];

  int blk = blockIdx.x;
  int g = blk >> 8;
  int r8 = blk & 255;
  int b = r8 >> 3, ot = r8 & 7;
  int obase = ot * 128;
  int t = threadIdx.x;
  int lane = t & 63, wave = t >> 6;
  int ln15 = lane & 15, kh = lane >> 4;

  int rA = t >> 2, qA = t & 3;
  int qs = qA ^ ((rA >> 1) & 3);

  const short* gA_h = (const short*)N2h + ((size_t)b * IDF + rA) * KHC;
  const short* gA_l = (const short*)N2l + ((size_t)b * IDF + rA) * KHC;
  const short* gB_h = (const short*)Wh;
  const short* gB_l = (const short*)Wl;

  f32x4 acc[4][2] = {};

  int offA[4], offB[2];
#pragma unroll
  for (int r = 0; r < 4; ++r) {
    int row = r * 16 + ln15;
    offA[r] = row * 32 + ((kh ^ ((row >> 1) & 3)) * 8);
  }
#pragma unroll
  for (int c = 0; c < 2; ++c) {
    int row = wave * 32 + c * 16 + ln15;
    offB[c] = row * 32 + ((kh ^ ((row >> 1) & 3)) * 8);
  }

  int kbase = g * (KHC / 2);
#pragma unroll 1
  for (int k0 = 0; k0 < KHC / 2; k0 += 32) {
    int kk0 = kbase + k0;
    int h = kk0 >> 8, cbase = kk0 & 255;
    int4 va_h = *reinterpret_cast<const int4*>(&gA_h[kk0 + qA * 8]);
    int4 va_l = *reinterpret_cast<const int4*>(&gA_l[kk0 + qA * 8]);
    int4 vb_h[2], vb_l[2];
#pragma unroll
    for (int j = 0; j < 2; ++j) {
      size_t ga = ((size_t)h * SSZ + obase + j * 64 + rA) * CDF + cbase + qA * 8;
      vb_h[j] = *reinterpret_cast<const int4*>(&gB_h[ga]);
      vb_l[j] = *reinterpret_cast<const int4*>(&gB_l[ga]);
    }
    __syncthreads();
    *reinterpret_cast<int4*>(&Ah[rA * 32 + qs * 8]) = va_h;
    *reinterpret_cast<int4*>(&Al[rA * 32 + qs * 8]) = va_l;
#pragma unroll
    for (int j = 0; j < 2; ++j) {
      *reinterpret_cast<int4*>(&Bh[(j * 64 + rA) * 32 + qs * 8]) = vb_h[j];
      *reinterpret_cast<int4*>(&Bl[(j * 64 + rA) * 32 + qs * 8]) = vb_l[j];
    }
    __syncthreads();
    short8v fa_h[4], fa_l[4], fb_h[2], fb_l[2];
#pragma unroll
    for (int r = 0; r < 4; ++r) {
      fa_h[r] = *reinterpret_cast<const short8v*>(&Ah[offA[r]]);
      fa_l[r] = *reinterpret_cast<const short8v*>(&Al[offA[r]]);
    }
#pragma unroll
    for (int c = 0; c < 2; ++c) {
      fb_h[c] = *reinterpret_cast<const short8v*>(&Bh[offB[c]]);
      fb_l[c] = *reinterpret_cast<const short8v*>(&Bl[offB[c]]);
    }
#pragma unroll
    for (int r = 0; r < 4; ++r)
#pragma unroll
      for (int c = 0; c < 2; ++c) {
        acc[r][c] = __builtin_amdgcn_mfma_f32_16x16x32_bf16(fa_h[r], fb_h[c], acc[r][c], 0, 0, 0);
        acc[r][c] = __builtin_amdgcn_mfma_f32_16x16x32_bf16(fa_h[r], fb_l[c], acc[r][c], 0, 0, 0);
        acc[r][c] = __builtin_amdgcn_mfma_f32_16x16x32_bf16(fa_l[r], fb_h[c], acc[r][c], 0, 0, 0);
      }
  }

  float* dst = (g == 0) ? out0 : out1;
  int rowq = (lane >> 4) * 4;
#pragma unroll
  for (int r = 0; r < 4; ++r)
#pragma unroll
    for (int c = 0; c < 2; ++c)
#pragma unroll
      for (int reg = 0; reg < 4; ++reg)
        dst[((size_t)b * IDF + r * 16 + rowq + reg) * SSZ +
            obase + wave * 32 + c * 16 + ln15] = acc[r][c][reg];
}

// out += P
__global__ __launch_bounds__(256) void k_add(float* __restrict__ out,
                                             const float* __restrict__ P) {
  int idx = blockIdx.x * 256 + threadIdx.x;
  float4 a = reinterpret_cast<float4*>(out)[idx];
  float4 p = reinterpret_cast<const float4*>(P)[idx];
  a.x += p.x; a.y += p.y; a.z += p.z; a.w += p.w;
  reinterpret_cast<float4*>(out)[idx] = a;
}

// ---------------------------------------------------------------------------
// K5: attn_out[b][l][i] = sum_h attn[bh][i][l]
// ---------------------------------------------------------------------------
__global__ __launch_bounds__(256) void k_attnout(const float* __restrict__ attn,
                                                 float* __restrict__ outa) {
  __shared__ float T[64][65];
  int blk = blockIdx.x; int b = blk >> 2, lt = blk & 3;
  int l0 = lt * 64;
  int tid = threadIdx.x;
  float4 acc[4];
#pragma unroll
  for (int p = 0; p < 4; ++p) acc[p] = make_float4(0.f, 0.f, 0.f, 0.f);
  for (int h = 0; h < NH; ++h) {
    const float* src = attn + (size_t)(b * NH + h) * IDF * LL;
#pragma unroll
    for (int p = 0; p < 4; ++p) {
      int f = tid + p * 256;
      int i = f >> 4, lc = (f & 15) * 4;
      float4 v = *reinterpret_cast<const float4*>(&src[i * LL + l0 + lc]);
      acc[p].x += v.x; acc[p].y += v.y; acc[p].z += v.z; acc[p].w += v.w;
    }
  }
#pragma unroll
  for (int p = 0; p < 4; ++p) {
    int f = tid + p * 256;
    int i = f >> 4, lc = (f & 15) * 4;
    T[i][lc + 0] = acc[p].x; T[i][lc + 1] = acc[p].y;
    T[i][lc + 2] = acc[p].z; T[i][lc + 3] = acc[p].w;
  }
  __syncthreads();
#pragma unroll
  for (int p = 0; p < 4; ++p) {
    int f = tid + p * 256;
    int lr = f >> 4, ic = (f & 15) * 4;
    float4 v = {T[ic + 0][lr], T[ic + 1][lr], T[ic + 2][lr], T[ic + 3][lr]};
    *reinterpret_cast<float4*>(&outa[((size_t)b * LL + l0 + lr) * IDF + ic]) = v;
  }
}

// ---------------------------------------------------------------------------
extern "C" void kernel_launch(void* const* d_in, const int* in_sizes, int n_in,
                              void* d_out, int out_size, void* d_ws, size_t ws_size,
                              hipStream_t stream) {
  const float* wc  = (const float*)d_in[0];   // [32][64][1024]
  const float* ctx = (const float*)d_in[1];   // [32][256][256]
  const float* W   = (const float*)d_in[2];   // [8][1024][256]
  float* out = (float*)d_out;

  // Region A (4.19M floats): M (fp32) -> N2h/N2l (bf16)
  float* RA = (float*)d_ws;
  // Region B (4.19M floats): wc/Wt splits -> attn -> {Pbuf, Wh/Wl}
  float* RB = RA + (size_t)4194304;

  float* Mbuf = RA;
  __hip_bfloat16* N2h = (__hip_bfloat16*)RA;                 // 4.19M bf16
  __hip_bfloat16* N2l = N2h + (size_t)BB * IDF * KHC;        // 4.19M bf16

  __hip_bfloat16* wch = (__hip_bfloat16*)RB;                 // 2.1M bf16
  __hip_bfloat16* wcl = wch + (size_t)BB * IDF * SSZ;
  __hip_bfloat16* wth = wcl + (size_t)BB * IDF * SSZ;
  __hip_bfloat16* wtl = wth + (size_t)NH * CDF * SSZ;
  float* Abuf = RB;                                          // attn, 4.19M floats
  float* Pbuf = RB;                                          // 2.1M floats
  __hip_bfloat16* Wh = (__hip_bfloat16*)(RB + (size_t)2097152);
  __hip_bfloat16* Wl = Wh + (size_t)NH * SSZ * CDF;

  k_split_wc<<<2048, 256, 0, stream>>>(wc, wch, wcl);
  k_split_Wt<<<512, 256, 0, stream>>>(W, wth, wtl);
  k1_mfma   <<<BB * NH * 2, 256, 0, stream>>>(wch, wcl, wth, wtl, Mbuf);
  k_attn    <<<BB * NH * 2, 256, 0, stream>>>(Mbuf, ctx, Abuf);
  k_N2      <<<BB * NH * 2, 256, 0, stream>>>(Abuf, ctx, N2h, N2l);
  k_attnout <<<BB * 4, 256, 0, stream>>>(Abuf, out + (size_t)BB * IDF * SSZ);
  k_split_W <<<2048, 256, 0, stream>>>(W, Wh, Wl);
  k4_mfma   <<<512, 256, 0, stream>>>(N2h, N2l, Wh, Wl, out, Pbuf);
  k_add     <<<2048, 256, 0, stream>>>(out, Pbuf);
}

// Round 6
// 264.649 us; speedup vs baseline: 1.9338x; 1.0147x over previous
//
#include <hip/hip_runtime.h>
#include <hip/hip_bf16.h>

#define BB 32
#define IDF 64
#define CDF 256
#define SSZ 1024
#define NH 8
#define LL 256
#define KHC 2048   // NH*CDF

typedef __attribute__((ext_vector_type(8))) short short8v;   // 8 bf16 (4 VGPR)
typedef __attribute__((ext_vector_type(4))) float f32x4;     // MFMA acc

__device__ inline void split_bf16(float x, __hip_bfloat16& h, __hip_bfloat16& l) {
  h = __float2bfloat16(x);
  l = __float2bfloat16(x - __bfloat162float(h));
}

// ---------------------------------------------------------------------------
// Split wc (fp32) -> wch, wcl (bf16 hi/lo), same [b][i][o] layout.
// ---------------------------------------------------------------------------
__global__ __launch_bounds__(256) void k_split_wc(const float* __restrict__ wc,
                                                  __hip_bfloat16* __restrict__ wch,
                                                  __hip_bfloat16* __restrict__ wcl) {
  int idx = (blockIdx.x * 256 + threadIdx.x) * 4;
  float4 v = *reinterpret_cast<const float4*>(&wc[idx]);
  __align__(16) __hip_bfloat16 hb[4], lb[4];
  split_bf16(v.x, hb[0], lb[0]); split_bf16(v.y, hb[1], lb[1]);
  split_bf16(v.z, hb[2], lb[2]); split_bf16(v.w, hb[3], lb[3]);
  *reinterpret_cast<int2*>(&wch[idx]) = *reinterpret_cast<int2*>(hb);
  *reinterpret_cast<int2*>(&wcl[idx]) = *reinterpret_cast<int2*>(lb);
}

// ---------------------------------------------------------------------------
// Split W (fp32, [h][o][c]) -> Wh, Wl (bf16, same layout). For K4.
// ---------------------------------------------------------------------------
__global__ __launch_bounds__(256) void k_split_W(const float* __restrict__ W,
                                                 __hip_bfloat16* __restrict__ Wh,
                                                 __hip_bfloat16* __restrict__ Wl) {
  int idx = (blockIdx.x * 256 + threadIdx.x) * 4;
  float4 v = *reinterpret_cast<const float4*>(&W[idx]);
  __align__(16) __hip_bfloat16 hb[4], lb[4];
  split_bf16(v.x, hb[0], lb[0]); split_bf16(v.y, hb[1], lb[1]);
  split_bf16(v.z, hb[2], lb[2]); split_bf16(v.w, hb[3], lb[3]);
  *reinterpret_cast<int2*>(&Wh[idx]) = *reinterpret_cast<int2*>(hb);
  *reinterpret_cast<int2*>(&Wl[idx]) = *reinterpret_cast<int2*>(lb);
}

// ---------------------------------------------------------------------------
// Split+transpose W[h][o][c] (fp32) -> Wt hi/lo [h][c][o] (bf16). For K1.
// ---------------------------------------------------------------------------
__global__ __launch_bounds__(256) void k_split_Wt(const float* __restrict__ W,
                                                  __hip_bfloat16* __restrict__ wth,
                                                  __hip_bfloat16* __restrict__ wtl) {
  __shared__ float Tt[64][65];   // [c][o]
  int blk = blockIdx.x;
  int h = blk >> 6, ot = (blk >> 2) & 15, ct = blk & 3;
  int og = ot * 64, cg = ct * 64;
  int t = threadIdx.x;
  int o_l = t >> 4, c4 = (t & 15) * 4;
#pragma unroll
  for (int p = 0; p < 4; ++p) {
    int o = o_l + 16 * p;
    float4 v = *reinterpret_cast<const float4*>(
        &W[((size_t)h * SSZ + og + o) * CDF + cg + c4]);
    Tt[c4 + 0][o] = v.x; Tt[c4 + 1][o] = v.y;
    Tt[c4 + 2][o] = v.z; Tt[c4 + 3][o] = v.w;
  }
  __syncthreads();
  int c_l = t >> 2;
#pragma unroll
  for (int p = 0; p < 4; ++p) {
    int oq = (t & 3) + 4 * p;
    int o0 = oq * 4;
    __hip_bfloat16 hv[4], lv[4];
#pragma unroll
    for (int j = 0; j < 4; ++j)
      split_bf16(Tt[c_l][o0 + j], hv[j], lv[j]);
    size_t base = ((size_t)h * CDF + cg + c_l) * SSZ + og + o0;
#pragma unroll
    for (int j = 0; j < 4; ++j) { wth[base + j] = hv[j]; wtl[base + j] = lv[j]; }
  }
}

// ---------------------------------------------------------------------------
// K1 (MFMA, pipelined): M[bh][i][c] = sum_o wc[b][i][o] * W[h][o][c]
// grid 512: (bh, nh-half). Per block 64i x 128c. 4 waves x (64i x 32c).
// Double-buffered LDS, register prefetch, ONE barrier per k-step.
// ---------------------------------------------------------------------------
__global__ __launch_bounds__(256) void k1_mfma(const __hip_bfloat16* __restrict__ wch,
                                               const __hip_bfloat16* __restrict__ wcl,
                                               const __hip_bfloat16* __restrict__ wth,
                                               const __hip_bfloat16* __restrict__ wtl,
                                               float* __restrict__ Mout) {
  __shared__ __align__(16) short Ah[2][IDF * 32];
  __shared__ __align__(16) short Al[2][IDF * 32];
  __shared__ __align__(16) short Bh[2][128 * 32];
  __shared__ __align__(16) short Bl[2][128 * 32];

  int blk = blockIdx.x;
  int bh = blk >> 1, nh = blk & 1;
  int b = bh >> 3, h = bh & 7;
  int t = threadIdx.x;
  int lane = t & 63, wave = t >> 6;
  int ln15 = lane & 15, kh = lane >> 4;

  int rA = t >> 2, qA = t & 3;
  int qs = qA ^ ((rA >> 1) & 3);

  const short* gA_h = (const short*)wch + ((size_t)b * IDF + rA) * SSZ;
  const short* gA_l = (const short*)wcl + ((size_t)b * IDF + rA) * SSZ;
  const short* gB_h = (const short*)wth + ((size_t)(h * CDF + nh * 128)) * SSZ;
  const short* gB_l = (const short*)wtl + ((size_t)(h * CDF + nh * 128)) * SSZ;

  f32x4 acc[4][2] = {};

  int offA[4], offB[2];
#pragma unroll
  for (int r = 0; r < 4; ++r) {
    int row = r * 16 + ln15;
    offA[r] = row * 32 + ((kh ^ ((row >> 1) & 3)) * 8);
  }
#pragma unroll
  for (int c = 0; c < 2; ++c) {
    int row = wave * 32 + c * 16 + ln15;
    offB[c] = row * 32 + ((kh ^ ((row >> 1) & 3)) * 8);
  }

  int4 va_h, va_l, vb_h[2], vb_l[2];
  // prologue: G2R(k=0), R2LDS(buf 0)
  va_h = *reinterpret_cast<const int4*>(&gA_h[qA * 8]);
  va_l = *reinterpret_cast<const int4*>(&gA_l[qA * 8]);
#pragma unroll
  for (int j = 0; j < 2; ++j) {
    size_t ga = (size_t)(j * 64 + rA) * SSZ + qA * 8;
    vb_h[j] = *reinterpret_cast<const int4*>(&gB_h[ga]);
    vb_l[j] = *reinterpret_cast<const int4*>(&gB_l[ga]);
  }
  *reinterpret_cast<int4*>(&Ah[0][rA * 32 + qs * 8]) = va_h;
  *reinterpret_cast<int4*>(&Al[0][rA * 32 + qs * 8]) = va_l;
#pragma unroll
  for (int j = 0; j < 2; ++j) {
    *reinterpret_cast<int4*>(&Bh[0][(j * 64 + rA) * 32 + qs * 8]) = vb_h[j];
    *reinterpret_cast<int4*>(&Bl[0][(j * 64 + rA) * 32 + qs * 8]) = vb_l[j];
  }

#pragma unroll 1
  for (int ks = 0; ks < 32; ++ks) {
    int cur = ks & 1;
    __syncthreads();               // buf[cur] writes visible; prev reads drained
    if (ks < 31) {                 // issue next k-step's global loads EARLY
      int k0 = (ks + 1) * 32;
      va_h = *reinterpret_cast<const int4*>(&gA_h[k0 + qA * 8]);
      va_l = *reinterpret_cast<const int4*>(&gA_l[k0 + qA * 8]);
#pragma unroll
      for (int j = 0; j < 2; ++j) {
        size_t ga = (size_t)(j * 64 + rA) * SSZ + k0 + qA * 8;
        vb_h[j] = *reinterpret_cast<const int4*>(&gB_h[ga]);
        vb_l[j] = *reinterpret_cast<const int4*>(&gB_l[ga]);
      }
    }
    short8v fa_h[4], fa_l[4], fb_h[2], fb_l[2];
#pragma unroll
    for (int r = 0; r < 4; ++r) {
      fa_h[r] = *reinterpret_cast<const short8v*>(&Ah[cur][offA[r]]);
      fa_l[r] = *reinterpret_cast<const short8v*>(&Al[cur][offA[r]]);
    }
#pragma unroll
    for (int c = 0; c < 2; ++c) {
      fb_h[c] = *reinterpret_cast<const short8v*>(&Bh[cur][offB[c]]);
      fb_l[c] = *reinterpret_cast<const short8v*>(&Bl[cur][offB[c]]);
    }
#pragma unroll
    for (int r = 0; r < 4; ++r)
#pragma unroll
      for (int c = 0; c < 2; ++c) {
        acc[r][c] = __builtin_amdgcn_mfma_f32_16x16x32_bf16(fa_h[r], fb_h[c], acc[r][c], 0, 0, 0);
        acc[r][c] = __builtin_amdgcn_mfma_f32_16x16x32_bf16(fa_h[r], fb_l[c], acc[r][c], 0, 0, 0);
        acc[r][c] = __builtin_amdgcn_mfma_f32_16x16x32_bf16(fa_l[r], fb_h[c], acc[r][c], 0, 0, 0);
      }
    if (ks < 31) {                 // write prefetched data to the other buffer
      int nxt = cur ^ 1;
      *reinterpret_cast<int4*>(&Ah[nxt][rA * 32 + qs * 8]) = va_h;
      *reinterpret_cast<int4*>(&Al[nxt][rA * 32 + qs * 8]) = va_l;
#pragma unroll
      for (int j = 0; j < 2; ++j) {
        *reinterpret_cast<int4*>(&Bh[nxt][(j * 64 + rA) * 32 + qs * 8]) = vb_h[j];
        *reinterpret_cast<int4*>(&Bl[nxt][(j * 64 + rA) * 32 + qs * 8]) = vb_l[j];
      }
    }
  }

  float* out = Mout + (size_t)bh * IDF * CDF + nh * 128;
  int rowq = (lane >> 4) * 4;
#pragma unroll
  for (int r = 0; r < 4; ++r)
#pragma unroll
    for (int c = 0; c < 2; ++c)
#pragma unroll
      for (int reg = 0; reg < 4; ++reg)
        out[(r * 16 + rowq + reg) * CDF + wave * 32 + c * 16 + ln15] = acc[r][c][reg];
}

// ---------------------------------------------------------------------------
// K2: logits[bh][i][l] = sum_c M[bh][i][c] * ctx[b][c][l]; softmax over l.
// grid 512: (bh, i-half of 32). acc[4][8].
// ---------------------------------------------------------------------------
__global__ __launch_bounds__(256) void k_attn(const float* __restrict__ Mm,
                                              const float* __restrict__ ctx,
                                              float* __restrict__ attn) {
  __shared__ float As[32][32];
  __shared__ float Bs[32][LL];
  int blk = blockIdx.x;
  int bh = blk >> 1, ih = blk & 1;
  int b = bh >> 3;
  int ibase = ih * 32;
  const float* A  = Mm + ((size_t)bh * IDF + ibase) * CDF;
  const float* Bm = ctx + (size_t)b * CDF * LL;
  int tid = threadIdx.x;
  int tc = tid & 31, ti = tid >> 5;
  int c0 = tc * 8, i0 = ti * 4;
  float acc[4][8];
#pragma unroll
  for (int r = 0; r < 4; ++r)
#pragma unroll
    for (int s = 0; s < 8; ++s) acc[r][s] = 0.f;

  for (int k0 = 0; k0 < CDF; k0 += 32) {
    {                                        // A tile: 32 rows x 8 f4
      int row = tid >> 3, seg = tid & 7;
      *reinterpret_cast<float4*>(&As[row][seg * 4]) =
          *reinterpret_cast<const float4*>(&A[row * CDF + k0 + seg * 4]);
    }
#pragma unroll
    for (int p = 0; p < 8; ++p) {            // B tile: 32 rows x 64 f4
      int f = tid + p * 256;
      int kk = f >> 6, cs = f & 63;
      *reinterpret_cast<float4*>(&Bs[kk][cs * 4]) =
          *reinterpret_cast<const float4*>(&Bm[(size_t)(k0 + kk) * LL + cs * 4]);
    }
    __syncthreads();
#pragma unroll
    for (int kq = 0; kq < 8; ++kq) {
      float4 av[4];
#pragma unroll
      for (int r = 0; r < 4; ++r)
        av[r] = *reinterpret_cast<const float4*>(&As[i0 + r][kq * 4]);
#pragma unroll
      for (int kk = 0; kk < 4; ++kk) {
        float4 b0 = *reinterpret_cast<const float4*>(&Bs[kq * 4 + kk][c0]);
        float4 b1 = *reinterpret_cast<const float4*>(&Bs[kq * 4 + kk][c0 + 4]);
        float bv[8] = {b0.x, b0.y, b0.z, b0.w, b1.x, b1.y, b1.z, b1.w};
#pragma unroll
        for (int r = 0; r < 4; ++r) {
          float a = (kk == 0) ? av[r].x : (kk == 1) ? av[r].y : (kk == 2) ? av[r].z : av[r].w;
#pragma unroll
          for (int s = 0; s < 8; ++s) acc[r][s] += a * bv[s];
        }
      }
    }
    __syncthreads();
  }
  float* out = attn + ((size_t)bh * IDF + ibase) * LL;
#pragma unroll
  for (int r = 0; r < 4; ++r) {
    float mx = acc[r][0];
#pragma unroll
    for (int s = 1; s < 8; ++s) mx = fmaxf(mx, acc[r][s]);
#pragma unroll
    for (int m = 16; m >= 1; m >>= 1) mx = fmaxf(mx, __shfl_xor(mx, m, 64));
    float ex[8]; float sum = 0.f;
#pragma unroll
    for (int s = 0; s < 8; ++s) { ex[s] = __expf(acc[r][s] - mx); sum += ex[s]; }
#pragma unroll
    for (int m = 16; m >= 1; m >>= 1) sum += __shfl_xor(sum, m, 64);
    float inv = 1.f / sum;
    float4 v0 = {ex[0] * inv, ex[1] * inv, ex[2] * inv, ex[3] * inv};
    float4 v1 = {ex[4] * inv, ex[5] * inv, ex[6] * inv, ex[7] * inv};
    *reinterpret_cast<float4*>(&out[(i0 + r) * LL + c0]) = v0;
    *reinterpret_cast<float4*>(&out[(i0 + r) * LL + c0 + 4]) = v1;
  }
}

// ---------------------------------------------------------------------------
// K3: N2{h,l}[b][i][h*256+c] = split(sum_l attn[bh][i][l]*ctx[b][c][l])
// grid 512: (bh, c-half of 128). acc[4][8].
// ---------------------------------------------------------------------------
__global__ __launch_bounds__(256) void k_N2(const float* __restrict__ attn,
                                            const float* __restrict__ ctx,
                                            __hip_bfloat16* __restrict__ N2h,
                                            __hip_bfloat16* __restrict__ N2l) {
  __shared__ float As[IDF][32];    // [i][l]
  __shared__ float Bs[32][132];    // [l][c], padded
  int blk = blockIdx.x;
  int bh = blk >> 1, ch = blk & 1;
  int b = bh >> 3, h = bh & 7;
  int cgbase = ch * 128;
  const float* A  = attn + (size_t)bh * IDF * LL;
  const float* Cm = ctx + ((size_t)b * CDF + cgbase) * LL;
  int tid = threadIdx.x;
  int tc = tid & 15, ti = tid >> 4;
  int c0 = tc * 8, i0 = ti * 4;
  float acc[4][8];
#pragma unroll
  for (int r = 0; r < 4; ++r)
#pragma unroll
    for (int s = 0; s < 8; ++s) acc[r][s] = 0.f;

  for (int l0 = 0; l0 < LL; l0 += 32) {
#pragma unroll
    for (int p = 0; p < 2; ++p) {            // attn tile: 64 rows x 8 f4
      int f = tid + p * 256;
      int row = f >> 3, seg = f & 7;
      *reinterpret_cast<float4*>(&As[row][seg * 4]) =
          *reinterpret_cast<const float4*>(&A[row * LL + l0 + seg * 4]);
    }
#pragma unroll
    for (int p = 0; p < 4; ++p) {            // ctx tile: transpose-stage 128 rows
      int f = tid + p * 256;
      int c = f >> 3, seg = f & 7;
      float4 v = *reinterpret_cast<const float4*>(&Cm[(size_t)c * LL + l0 + seg * 4]);
      Bs[seg * 4 + 0][c] = v.x; Bs[seg * 4 + 1][c] = v.y;
      Bs[seg * 4 + 2][c] = v.z; Bs[seg * 4 + 3][c] = v.w;
    }
    __syncthreads();
#pragma unroll
    for (int kq = 0; kq < 8; ++kq) {
      float4 av[4];
#pragma unroll
      for (int r = 0; r < 4; ++r)
        av[r] = *reinterpret_cast<const float4*>(&As[i0 + r][kq * 4]);
#pragma unroll
      for (int kk = 0; kk < 4; ++kk) {
        float4 b0 = *reinterpret_cast<const float4*>(&Bs[kq * 4 + kk][c0]);
        float4 b1 = *reinterpret_cast<const float4*>(&Bs[kq * 4 + kk][c0 + 4]);
        float bv[8] = {b0.x, b0.y, b0.z, b0.w, b1.x, b1.y, b1.z, b1.w};
#pragma unroll
        for (int r = 0; r < 4; ++r) {
          float a = (kk == 0) ? av[r].x : (kk == 1) ? av[r].y : (kk == 2) ? av[r].z : av[r].w;
#pragma unroll
          for (int s = 0; s < 8; ++s) acc[r][s] += a * bv[s];
        }
      }
    }
    __syncthreads();
  }
  // epilogue: split to bf16 hi/lo, write [b][i][h*256 + cgbase + c]
  size_t base = (size_t)b * IDF * KHC + h * CDF + cgbase;
#pragma unroll
  for (int r = 0; r < 4; ++r) {
    __align__(16) __hip_bfloat16 hb[8], lb[8];
#pragma unroll
    for (int s = 0; s < 8; ++s) split_bf16(acc[r][s], hb[s], lb[s]);
    size_t idx = base + (size_t)(i0 + r) * KHC + c0;
    *reinterpret_cast<int4*>(&N2h[idx]) = *reinterpret_cast<int4*>(hb);
    *reinterpret_cast<int4*>(&N2l[idx]) = *reinterpret_cast<int4*>(lb);
  }
}

// ---------------------------------------------------------------------------
// K4 (MFMA, pipelined): ctx_out[b][i][o] = sum_{h,c} N2[b][i][hc] * W[h][o][c]
// grid 512: g(2 K-halves) x b(32) x ot(8 of 128 o). 4 waves x (64i x 32o).
// Double-buffered LDS, register prefetch, ONE barrier per k-step.
// ---------------------------------------------------------------------------
__global__ __launch_bounds__(256) void k4_mfma(const __hip_bfloat16* __restrict__ N2h,
                                               const __hip_bfloat16* __restrict__ N2l,
                                               const __hip_bfloat16* __restrict__ Wh,
                                               const __hip_bfloat16* __restrict__ Wl,
                                               float* __restrict__ out0,
                                               float* __restrict__ out1) {
  __shared__ __align__(16) short Ah[2][IDF * 32];
  __shared__ __align__(16) short Al[2][IDF * 32];
  __shared__ __align__(16) short Bh[2][128 * 32];
  __shared__ __align__(16) short Bl[2][128 * 32];

  int blk = blockIdx.x;
  int g = blk >> 8;
  int r8 = blk & 255;
  int b = r8 >> 3, ot = r8 & 7;
  int obase = ot * 128;
  int t = threadIdx.x;
  int lane = t & 63, wave = t >> 6;
  int ln15 = lane & 15, kh = lane >> 4;

  int rA = t >> 2, qA = t & 3;
  int qs = qA ^ ((rA >> 1) & 3);

  const short* gA_h = (const short*)N2h + ((size_t)b * IDF + rA) * KHC;
  const short* gA_l = (const short*)N2l + ((size_t)b * IDF + rA) * KHC;
  const short* gB_h = (const short*)Wh;
  const short* gB_l = (const short*)Wl;

  f32x4 acc[4][2] = {};

  int offA[4], offB[2];
#pragma unroll
  for (int r = 0; r < 4; ++r) {
    int row = r * 16 + ln15;
    offA[r] = row * 32 + ((kh ^ ((row >> 1) & 3)) * 8);
  }
#pragma unroll
  for (int c = 0; c < 2; ++c) {
    int row = wave * 32 + c * 16 + ln15;
    offB[c] = row * 32 + ((kh ^ ((row >> 1) & 3)) * 8);
  }

  int kbase = g * (KHC / 2);

  int4 va_h, va_l, vb_h[2], vb_l[2];
  // prologue: G2R(ks=0), R2LDS(buf 0)
  {
    int kk0 = kbase;
    int h = kk0 >> 8, cbase = kk0 & 255;
    va_h = *reinterpret_cast<const int4*>(&gA_h[kk0 + qA * 8]);
    va_l = *reinterpret_cast<const int4*>(&gA_l[kk0 + qA * 8]);
#pragma unroll
    for (int j = 0; j < 2; ++j) {
      size_t ga = ((size_t)h * SSZ + obase + j * 64 + rA) * CDF + cbase + qA * 8;
      vb_h[j] = *reinterpret_cast<const int4*>(&gB_h[ga]);
      vb_l[j] = *reinterpret_cast<const int4*>(&gB_l[ga]);
    }
  }
  *reinterpret_cast<int4*>(&Ah[0][rA * 32 + qs * 8]) = va_h;
  *reinterpret_cast<int4*>(&Al[0][rA * 32 + qs * 8]) = va_l;
#pragma unroll
  for (int j = 0; j < 2; ++j) {
    *reinterpret_cast<int4*>(&Bh[0][(j * 64 + rA) * 32 + qs * 8]) = vb_h[j];
    *reinterpret_cast<int4*>(&Bl[0][(j * 64 + rA) * 32 + qs * 8]) = vb_l[j];
  }

#pragma unroll 1
  for (int ks = 0; ks < 32; ++ks) {
    int cur = ks & 1;
    __syncthreads();               // buf[cur] writes visible; prev reads drained
    if (ks < 31) {                 // issue next k-step's global loads EARLY
      int kk0 = kbase + (ks + 1) * 32;
      int h = kk0 >> 8, cbase = kk0 & 255;
      va_h = *reinterpret_cast<const int4*>(&gA_h[kk0 + qA * 8]);
      va_l = *reinterpret_cast<const int4*>(&gA_l[kk0 + qA * 8]);
#pragma unroll
      for (int j = 0; j < 2; ++j) {
        size_t ga = ((size_t)h * SSZ + obase + j * 64 + rA) * CDF + cbase + qA * 8;
        vb_h[j] = *reinterpret_cast<const int4*>(&gB_h[ga]);
        vb_l[j] = *reinterpret_cast<const int4*>(&gB_l[ga]);
      }
    }
    short8v fa_h[4], fa_l[4], fb_h[2], fb_l[2];
#pragma unroll
    for (int r = 0; r < 4; ++r) {
      fa_h[r] = *reinterpret_cast<const short8v*>(&Ah[cur][offA[r]]);
      fa_l[r] = *reinterpret_cast<const short8v*>(&Al[cur][offA[r]]);
    }
#pragma unroll
    for (int c = 0; c < 2; ++c) {
      fb_h[c] = *reinterpret_cast<const short8v*>(&Bh[cur][offB[c]]);
      fb_l[c] = *reinterpret_cast<const short8v*>(&Bl[cur][offB[c]]);
    }
#pragma unroll
    for (int r = 0; r < 4; ++r)
#pragma unroll
      for (int c = 0; c < 2; ++c) {
        acc[r][c] = __builtin_amdgcn_mfma_f32_16x16x32_bf16(fa_h[r], fb_h[c], acc[r][c], 0, 0, 0);
        acc[r][c] = __builtin_amdgcn_mfma_f32_16x16x32_bf16(fa_h[r], fb_l[c], acc[r][c], 0, 0, 0);
        acc[r][c] = __builtin_amdgcn_mfma_f32_16x16x32_bf16(fa_l[r], fb_h[c], acc[r][c], 0, 0, 0);
      }
    if (ks < 31) {                 // write prefetched data to the other buffer
      int nxt = cur ^ 1;
      *reinterpret_cast<int4*>(&Ah[nxt][rA * 32 + qs * 8]) = va_h;
      *reinterpret_cast<int4*>(&Al[nxt][rA * 32 + qs * 8]) = va_l;
#pragma unroll
      for (int j = 0; j < 2; ++j) {
        *reinterpret_cast<int4*>(&Bh[nxt][(j * 64 + rA) * 32 + qs * 8]) = vb_h[j];
        *reinterpret_cast<int4*>(&Bl[nxt][(j * 64 + rA) * 32 + qs * 8]) = vb_l[j];
      }
    }
  }

  float* dst = (g == 0) ? out0 : out1;
  int rowq = (lane >> 4) * 4;
#pragma unroll
  for (int r = 0; r < 4; ++r)
#pragma unroll
    for (int c = 0; c < 2; ++c)
#pragma unroll
      for (int reg = 0; reg < 4; ++reg)
        dst[((size_t)b * IDF + r * 16 + rowq + reg) * SSZ +
            obase + wave * 32 + c * 16 + ln15] = acc[r][c][reg];
}

// out += P
__global__ __launch_bounds__(256) void k_add(float* __restrict__ out,
                                             const float* __restrict__ P) {
  int idx = blockIdx.x * 256 + threadIdx.x;
  float4 a = reinterpret_cast<float4*>(out)[idx];
  float4 p = reinterpret_cast<const float4*>(P)[idx];
  a.x += p.x; a.y += p.y; a.z += p.z; a.w += p.w;
  reinterpret_cast<float4*>(out)[idx] = a;
}

// ---------------------------------------------------------------------------
// K5: attn_out[b][l][i] = sum_h attn[bh][i][l]
// ---------------------------------------------------------------------------
__global__ __launch_bounds__(256) void k_attnout(const float* __restrict__ attn,
                                                 float* __restrict__ outa) {
  __shared__ float T[64][65];
  int blk = blockIdx.x; int b = blk >> 2, lt = blk & 3;
  int l0 = lt * 64;
  int tid = threadIdx.x;
  float4 acc[4];
#pragma unroll
  for (int p = 0; p < 4; ++p) acc[p] = make_float4(0.f, 0.f, 0.f, 0.f);
  for (int h = 0; h < NH; ++h) {
    const float* src = attn + (size_t)(b * NH + h) * IDF * LL;
#pragma unroll
    for (int p = 0; p < 4; ++p) {
      int f = tid + p * 256;
      int i = f >> 4, lc = (f & 15) * 4;
      float4 v = *reinterpret_cast<const float4*>(&src[i * LL + l0 + lc]);
      acc[p].x += v.x; acc[p].y += v.y; acc[p].z += v.z; acc[p].w += v.w;
    }
  }
#pragma unroll
  for (int p = 0; p < 4; ++p) {
    int f = tid + p * 256;
    int i = f >> 4, lc = (f & 15) * 4;
    T[i][lc + 0] = acc[p].x; T[i][lc + 1] = acc[p].y;
    T[i][lc + 2] = acc[p].z; T[i][lc + 3] = acc[p].w;
  }
  __syncthreads();
#pragma unroll
  for (int p = 0; p < 4; ++p) {
    int f = tid + p * 256;
    int lr = f >> 4, ic = (f & 15) * 4;
    float4 v = {T[ic + 0][lr], T[ic + 1][lr], T[ic + 2][lr], T[ic + 3][lr]};
    *reinterpret_cast<float4*>(&outa[((size_t)b * LL + l0 + lr) * IDF + ic]) = v;
  }
}

// ---------------------------------------------------------------------------
extern "C" void kernel_launch(void* const* d_in, const int* in_sizes, int n_in,
                              void* d_out, int out_size, void* d_ws, size_t ws_size,
                              hipStream_t stream) {
  const float* wc  = (const float*)d_in[0];   // [32][64][1024]
  const float* ctx = (const float*)d_in[1];   // [32][256][256]
  const float* W   = (const float*)d_in[2];   // [8][1024][256]
  float* out = (float*)d_out;

  // Region A (4.19M floats): M (fp32) -> N2h/N2l (bf16)
  float* RA = (float*)d_ws;
  // Region B (4.19M floats): wc/Wt splits -> attn -> {Pbuf, Wh/Wl}
  float* RB = RA + (size_t)4194304;

  float* Mbuf = RA;
  __hip_bfloat16* N2h = (__hip_bfloat16*)RA;                 // 4.19M bf16
  __hip_bfloat16* N2l = N2h + (size_t)BB * IDF * KHC;        // 4.19M bf16

  __hip_bfloat16* wch = (__hip_bfloat16*)RB;                 // 2.1M bf16
  __hip_bfloat16* wcl = wch + (size_t)BB * IDF * SSZ;
  __hip_bfloat16* wth = wcl + (size_t)BB * IDF * SSZ;
  __hip_bfloat16* wtl = wth + (size_t)NH * CDF * SSZ;
  float* Abuf = RB;                                          // attn, 4.19M floats
  float* Pbuf = RB;                                          // 2.1M floats
  __hip_bfloat16* Wh = (__hip_bfloat16*)(RB + (size_t)2097152);
  __hip_bfloat16* Wl = Wh + (size_t)NH * SSZ * CDF;

  k_split_wc<<<2048, 256, 0, stream>>>(wc, wch, wcl);
  k_split_Wt<<<512, 256, 0, stream>>>(W, wth, wtl);
  k1_mfma   <<<BB * NH * 2, 256, 0, stream>>>(wch, wcl, wth, wtl, Mbuf);
  k_attn    <<<BB * NH * 2, 256, 0, stream>>>(Mbuf, ctx, Abuf);
  k_N2      <<<BB * NH * 2, 256, 0, stream>>>(Abuf, ctx, N2h, N2l);
  k_attnout <<<BB * 4, 256, 0, stream>>>(Abuf, out + (size_t)BB * IDF * SSZ);
  k_split_W <<<2048, 256, 0, stream>>>(W, Wh, Wl);
  k4_mfma   <<<512, 256, 0, stream>>>(N2h, N2l, Wh, Wl, out, Pbuf);
  k_add     <<<2048, 256, 0, stream>>>(out, Pbuf);
}